// Round 7
// baseline (3535.970 us; speedup 1.0000x reference)
//
#include <hip/hip_runtime.h>
#include <stdint.h>

#define NS 150
#define D_IN 1024
#define D_H 512
#define D_OUT 256
#define BATCH 32

// ---- workspace layout (float offsets) ----
#define OFF_XT    0u                // 1024*32      = 32768   xT[i][b]
#define OFF_MS1   32768u            // float2[1024*512] (mu,std) at [i][h]
#define OFF_MS2   1081344u          // float2[512*256]  (mu,std) at [hh][o]
#define OFF_B1S   1343488u          // 150*512  = 76800   b1s[n][h]
#define OFF_B2S   1420288u          // 150*256  = 38400   b2s[n][o]
#define OFF_HT    1458688u          // 150*512*32 = 2457600  hT[n][h][b]

// ---------- threefry-2x32 (JAX-exact, 20 rounds) ----------
#define ROTL32(x, r) __builtin_rotateleft32((x), (r))

__host__ __device__ __forceinline__ void threefry2x32(uint32_t k0, uint32_t k1,
                                                      uint32_t x0, uint32_t x1,
                                                      uint32_t& o0, uint32_t& o1) {
  uint32_t k2 = k0 ^ k1 ^ 0x1BD11BDAu;
  x0 += k0; x1 += k1;
#define TFR(r) { x0 += x1; x1 = ROTL32(x1, r); x1 ^= x0; }
  TFR(13) TFR(15) TFR(26) TFR(6)
  x0 += k1; x1 += k2 + 1u;
  TFR(17) TFR(29) TFR(16) TFR(24)
  x0 += k2; x1 += k0 + 2u;
  TFR(13) TFR(15) TFR(26) TFR(6)
  x0 += k0; x1 += k1 + 3u;
  TFR(17) TFR(29) TFR(16) TFR(24)
  x0 += k1; x1 += k2 + 4u;
  TFR(13) TFR(15) TFR(26) TFR(6)
  x0 += k2; x1 += k0 + 5u;
#undef TFR
  o0 = x0; o1 = x1;
}

// bits -> uniform(-1,1) -> sqrt2*erfinv; native log/sqrt; sqrt2 folded in coeffs.
__device__ __forceinline__ float tf_normal(uint32_t k0, uint32_t k1, uint32_t idx) {
  uint32_t o0, o1;
  threefry2x32(k0, k1, 0u, idx, o0, o1);
  uint32_t bits = o0 ^ o1;
  uint32_t fb = (bits >> 9) | 0x3F800000u;
  float m = __uint_as_float(fb);                 // [1,2)
  const float lo = -0.99999994f;                 // nextafter(-1,0)
  float u = fmaxf(fmaf(m, 2.0f, -3.0f), lo);
  float t = fmaf(u, -u, 1.0f);                   // 1-u^2, single rounding
  float w = -0.69314718056f * __builtin_amdgcn_logf(t);   // -ln(1-u^2)
  const float S = 1.41421354f;
  float p;
  if (w < 5.0f) {
    float ww = w - 2.5f;
    p = S * 2.81022636e-08f;
    p = fmaf(p, ww, S * 3.43273939e-07f);
    p = fmaf(p, ww, S * -3.5233877e-06f);
    p = fmaf(p, ww, S * -4.39150654e-06f);
    p = fmaf(p, ww, S * 0.00021858087f);
    p = fmaf(p, ww, S * -0.00125372503f);
    p = fmaf(p, ww, S * -0.00417768164f);
    p = fmaf(p, ww, S * 0.246640727f);
    p = fmaf(p, ww, S * 1.50140941f);
  } else {
    float ww = __builtin_amdgcn_sqrtf(w) - 3.0f;
    p = S * -0.000200214257f;
    p = fmaf(p, ww, S * 0.000100950558f);
    p = fmaf(p, ww, S * 0.00134934322f);
    p = fmaf(p, ww, S * -0.00367342844f);
    p = fmaf(p, ww, S * 0.00573950773f);
    p = fmaf(p, ww, S * -0.0076224613f);
    p = fmaf(p, ww, S * 0.00943887047f);
    p = fmaf(p, ww, S * 1.00167406f);
    p = fmaf(p, ww, S * 2.83297682f);
  }
  return p * u;
}

// ---------- prep: LDS-tiled transposes into interleaved (mu,std) + biases ----------
__global__ __launch_bounds__(256) void prep_kernel(
    const float* __restrict__ x,
    const float* __restrict__ muW1, const float* __restrict__ vW1,
    const float* __restrict__ muW2, const float* __restrict__ vW2,
    const float* __restrict__ mub1, const float* __restrict__ vb1,
    const float* __restrict__ mub2, const float* __restrict__ vb2,
    float* __restrict__ ws,
    uint32_t kb1_0, uint32_t kb1_1, uint32_t kb2_0, uint32_t kb2_1) {
  __shared__ float2 tl[32][33];
  int bb = blockIdx.x;
  int tx = threadIdx.x & 31;
  int ty = threadIdx.x >> 5;        // 0..7

  if (bb < 512) {                   // W1 tile
    int i0 = (bb & 31) * 32, h0 = (bb >> 5) * 32;
#pragma unroll
    for (int r = 0; r < 4; ++r) {
      int h = h0 + ty + r * 8, i = i0 + tx;
      float m = muW1[h * D_IN + i];
      float s = expf(vW1[h * D_IN + i]);
      tl[ty + r * 8][tx] = make_float2(m, s);
    }
    __syncthreads();
    float2* ms1 = (float2*)(ws + OFF_MS1);
#pragma unroll
    for (int r = 0; r < 4; ++r) {
      int i = i0 + ty + r * 8, h = h0 + tx;
      ms1[i * D_H + h] = tl[tx][ty + r * 8];
    }
  } else if (bb < 640) {            // W2 tile
    int t = bb - 512;
    int h0 = (t & 15) * 32, o0 = (t >> 4) * 32;
#pragma unroll
    for (int r = 0; r < 4; ++r) {
      int o = o0 + ty + r * 8, hh = h0 + tx;
      float m = muW2[o * D_H + hh];
      float s = expf(vW2[o * D_H + hh]);
      tl[ty + r * 8][tx] = make_float2(m, s);
    }
    __syncthreads();
    float2* ms2 = (float2*)(ws + OFF_MS2);
#pragma unroll
    for (int r = 0; r < 4; ++r) {
      int hh = h0 + ty + r * 8, o = o0 + tx;
      ms2[hh * D_OUT + o] = tl[tx][ty + r * 8];
    }
  } else if (bb < 672) {            // xT tile
    int i0 = (bb - 640) * 32;
#pragma unroll
    for (int r = 0; r < 4; ++r) {
      int b = ty + r * 8, i = i0 + tx;
      tl[ty + r * 8][tx].x = x[b * D_IN + i];
    }
    __syncthreads();
#pragma unroll
    for (int r = 0; r < 4; ++r) {
      int i = i0 + ty + r * 8, b = tx;
      ws[OFF_XT + i * BATCH + b] = tl[tx][ty + r * 8].x;
    }
  } else if (bb < 747) {            // b1s
    int t0 = (bb - 672) * 1024 + threadIdx.x;
#pragma unroll
    for (int r = 0; r < 4; ++r) {
      int t = t0 + r * 256;
      int h = t & 511;
      float eps = tf_normal(kb1_0, kb1_1, (uint32_t)t);
      ws[OFF_B1S + t] = fmaf(eps, expf(vb1[h]), mub1[h]);
    }
  } else {                          // b2s
    int t0 = (bb - 747) * 1024 + threadIdx.x;
#pragma unroll
    for (int r = 0; r < 4; ++r) {
      int t = t0 + r * 256;
      if (t < NS * D_OUT) {
        int o = t & 255;
        float eps = tf_normal(kb2_0, kb2_1, (uint32_t)t);
        ws[OFF_B2S + t] = fmaf(eps, expf(vb2[o]), mub2[o]);
      }
    }
  }
}

// ---------- layer 1 ----------
// 256-thr blocks (4 waves): thread = (chunk c = t>>5 in 0..7, pair = t&31).
// Group = 32 consecutive (n,h) pairs; 2400 groups; grid = 2048 = EXACT
// residency (8 blocks/CU x 4 waves = 32-wave cap), grid-stride loop so
// there is no dispatch tail (prev: 176-block tail at 2 waves/SIMD cost
// ~45% of runtime; occupancy counter 51%). LDS 8 KB/block.
#define L1_GROUPS 2400
#define L1_GRID   2048
__global__ __launch_bounds__(256, 8) void l1_kernel(
    const float* __restrict__ ws, float* __restrict__ hT,
    uint32_t k0, uint32_t k1) {
  const float* __restrict__ xT = ws + OFF_XT;
  const float2* __restrict__ ms1 = (const float2*)(ws + OFF_MS1);
  const float* __restrict__ b1s = ws + OFF_B1S;

  __shared__ float red[8][8][32];    // 8192 B; [chunk][b-slice][pair]

  int pair = threadIdx.x & 31;
  int c = threadIdx.x >> 5;          // 0..7 (half-wave uniform)

  for (int g = blockIdx.x; g < L1_GROUPS; g += L1_GRID) {
    int gid = g * 32 + pair;         // (n*512 + h)
    int h = gid & 511;

    float acc[BATCH];
#pragma unroll
    for (int b = 0; b < BATCH; ++b) acc[b] = 0.0f;

    uint32_t base = ((uint32_t)gid << 10) + (uint32_t)(c * 128);
    int i0 = c * 128;
#pragma unroll 4
    for (int ii = 0; ii < 128; ++ii) {
      int i = i0 + ii;
      float2 ms = ms1[i * D_H + h];             // half-wave 256B segments
      float eps = tf_normal(k0, k1, base + (uint32_t)ii);
      float wval = fmaf(eps, ms.y, ms.x);
      const float4* xp = (const float4*)(xT + i * BATCH);  // half-wave uniform
#pragma unroll
      for (int b4 = 0; b4 < 8; ++b4) {
        float4 xv = xp[b4];
        acc[b4 * 4 + 0] = fmaf(wval, xv.x, acc[b4 * 4 + 0]);
        acc[b4 * 4 + 1] = fmaf(wval, xv.y, acc[b4 * 4 + 1]);
        acc[b4 * 4 + 2] = fmaf(wval, xv.z, acc[b4 * 4 + 2]);
        acc[b4 * 4 + 3] = fmaf(wval, xv.w, acc[b4 * 4 + 3]);
      }
    }

    float bb = b1s[gid];
#pragma unroll
    for (int p4 = 0; p4 < 4; ++p4) {
#pragma unroll
      for (int j = 0; j < 8; ++j) red[c][j][pair] = acc[p4 * 8 + j];
      __syncthreads();
      // thread (c,pair) reduces output (gid(pair), b = p4*8 + c)
      float s = red[0][c][pair] + red[1][c][pair] + red[2][c][pair] + red[3][c][pair]
              + red[4][c][pair] + red[5][c][pair] + red[6][c][pair] + red[7][c][pair];
      hT[(size_t)gid * BATCH + p4 * 8 + c] = fmaxf(s + bb, 0.0f);
      __syncthreads();
    }
  }
}

// ---------- layer 2 ----------
// Same template: 256-thr blocks, 32 (n,o) pairs/group, 8 hh-chunks of 64.
// 1200 groups, grid = 1200 (< 2048 residency cap -> all resident, no tail).
__global__ __launch_bounds__(256, 8) void l2_kernel(
    const float* __restrict__ ws, float* __restrict__ y,
    uint32_t k0, uint32_t k1) {
  const float* __restrict__ hT = ws + OFF_HT;
  const float2* __restrict__ ms2 = (const float2*)(ws + OFF_MS2);
  const float* __restrict__ b2s = ws + OFF_B2S;

  __shared__ float red[8][8][32];    // 8192 B

  int pair = threadIdx.x & 31;
  int c = threadIdx.x >> 5;          // 0..7
  int g = blockIdx.x;
  int gid = g * 32 + pair;           // (n*256 + o)
  int n = __builtin_amdgcn_readfirstlane(gid >> 8);  // uniform: 32 | 256
  int o = gid & 255;

  float acc[BATCH];
#pragma unroll
  for (int b = 0; b < BATCH; ++b) acc[b] = 0.0f;

  uint32_t base = ((uint32_t)gid << 9) + (uint32_t)(c * 64);
  int h0 = c * 64;
  const float* hbase = hT + (size_t)n * (D_H * BATCH);
#pragma unroll 4
  for (int jj = 0; jj < 64; ++jj) {
    int hh = h0 + jj;
    float2 ms = ms2[hh * D_OUT + o];            // half-wave 256B segments
    float eps = tf_normal(k0, k1, base + (uint32_t)jj);
    float wval = fmaf(eps, ms.y, ms.x);
    const float4* hp = (const float4*)(hbase + hh * BATCH);  // half-wave uniform
#pragma unroll
    for (int b4 = 0; b4 < 8; ++b4) {
      float4 hv = hp[b4];
      acc[b4 * 4 + 0] = fmaf(wval, hv.x, acc[b4 * 4 + 0]);
      acc[b4 * 4 + 1] = fmaf(wval, hv.y, acc[b4 * 4 + 1]);
      acc[b4 * 4 + 2] = fmaf(wval, hv.z, acc[b4 * 4 + 2]);
      acc[b4 * 4 + 3] = fmaf(wval, hv.w, acc[b4 * 4 + 3]);
    }
  }

  float bb = b2s[gid];
#pragma unroll
  for (int p4 = 0; p4 < 4; ++p4) {
#pragma unroll
    for (int j = 0; j < 8; ++j) red[c][j][pair] = acc[p4 * 8 + j];
    __syncthreads();
    // thread (c,pair) reduces output (gid(pair), b = p4*8 + c)
    float s = red[0][c][pair] + red[1][c][pair] + red[2][c][pair] + red[3][c][pair]
            + red[4][c][pair] + red[5][c][pair] + red[6][c][pair] + red[7][c][pair];
    int b = p4 * 8 + c;
    y[(size_t)n * (BATCH * D_OUT) + b * D_OUT + o] = s + bb;  // o inner: coalesced/half-wave
    __syncthreads();
  }
}

extern "C" void kernel_launch(void* const* d_in, const int* in_sizes, int n_in,
                              void* d_out, int out_size, void* d_ws, size_t ws_size,
                              hipStream_t stream) {
  const float* x = (const float*)d_in[0];
  const float* muW1 = (const float*)d_in[1];
  const float* mub1 = (const float*)d_in[2];
  const float* muW2 = (const float*)d_in[3];
  const float* mub2 = (const float*)d_in[4];
  const float* vW1 = (const float*)d_in[5];
  const float* vb1 = (const float*)d_in[6];
  const float* vW2 = (const float*)d_in[7];
  const float* vb2 = (const float*)d_in[8];
  float* y = (float*)d_out;
  float* ws = (float*)d_ws;

  uint32_t nk[4][2];
  for (uint32_t j = 0; j < 4; ++j) {
    threefry2x32(0u, 42u, 0u, j, nk[j][0], nk[j][1]);
  }
  // eW1=nk[0], eb1=nk[1], eW2=nk[2], eb2=nk[3]

  prep_kernel<<<785, 256, 0, stream>>>(
      x, muW1, vW1, muW2, vW2, mub1, vb1, mub2, vb2, ws,
      nk[1][0], nk[1][1], nk[3][0], nk[3][1]);

  // l1: 2400 groups of 32 pairs, grid = 2048 (exact residency), stride loop
  l1_kernel<<<L1_GRID, 256, 0, stream>>>(ws, ws + OFF_HT, nk[0][0], nk[0][1]);

  // l2: 1200 groups of 32 pairs, all resident
  l2_kernel<<<NS * D_OUT / 32, 256, 0, stream>>>(ws, y, nk[2][0], nk[2][1]);
}

// Round 8
// 509.545 us; speedup vs baseline: 6.9395x; 6.9395x over previous
//
#include <hip/hip_runtime.h>
#include <stdint.h>

#define NS 150
#define D_IN 1024
#define D_H 512
#define D_OUT 256
#define BATCH 32

// ---- workspace layout (float offsets) ----
#define OFF_XT    0u                // 1024*32      = 32768   xT[i][b]
#define OFF_MS1   32768u            // float2[1024*512] (mu,std) at [i][h]
#define OFF_MS2   1081344u          // float2[512*256]  (mu,std) at [hh][o]
#define OFF_B1S   1343488u          // 150*512  = 76800   b1s[n][h]
#define OFF_B2S   1420288u          // 150*256  = 38400   b2s[n][o]
#define OFF_HT    1458688u          // 150*512*32 = 2457600  hT[n][h][b]

// ---------- threefry-2x32 (JAX-exact, 20 rounds) ----------
#define ROTL32(x, r) __builtin_rotateleft32((x), (r))

__host__ __device__ __forceinline__ void threefry2x32(uint32_t k0, uint32_t k1,
                                                      uint32_t x0, uint32_t x1,
                                                      uint32_t& o0, uint32_t& o1) {
  uint32_t k2 = k0 ^ k1 ^ 0x1BD11BDAu;
  x0 += k0; x1 += k1;
#define TFR(r) { x0 += x1; x1 = ROTL32(x1, r); x1 ^= x0; }
  TFR(13) TFR(15) TFR(26) TFR(6)
  x0 += k1; x1 += k2 + 1u;
  TFR(17) TFR(29) TFR(16) TFR(24)
  x0 += k2; x1 += k0 + 2u;
  TFR(13) TFR(15) TFR(26) TFR(6)
  x0 += k0; x1 += k1 + 3u;
  TFR(17) TFR(29) TFR(16) TFR(24)
  x0 += k1; x1 += k2 + 4u;
  TFR(13) TFR(15) TFR(26) TFR(6)
  x0 += k2; x1 += k0 + 5u;
#undef TFR
  o0 = x0; o1 = x1;
}

// bits -> uniform(-1,1) -> sqrt2*erfinv; native log/sqrt; sqrt2 folded in coeffs.
__device__ __forceinline__ float tf_normal(uint32_t k0, uint32_t k1, uint32_t idx) {
  uint32_t o0, o1;
  threefry2x32(k0, k1, 0u, idx, o0, o1);
  uint32_t bits = o0 ^ o1;
  uint32_t fb = (bits >> 9) | 0x3F800000u;
  float m = __uint_as_float(fb);                 // [1,2)
  const float lo = -0.99999994f;                 // nextafter(-1,0)
  float u = fmaxf(fmaf(m, 2.0f, -3.0f), lo);
  float t = fmaf(u, -u, 1.0f);                   // 1-u^2, single rounding
  float w = -0.69314718056f * __builtin_amdgcn_logf(t);   // -ln(1-u^2)
  const float S = 1.41421354f;
  float p;
  if (w < 5.0f) {
    float ww = w - 2.5f;
    p = S * 2.81022636e-08f;
    p = fmaf(p, ww, S * 3.43273939e-07f);
    p = fmaf(p, ww, S * -3.5233877e-06f);
    p = fmaf(p, ww, S * -4.39150654e-06f);
    p = fmaf(p, ww, S * 0.00021858087f);
    p = fmaf(p, ww, S * -0.00125372503f);
    p = fmaf(p, ww, S * -0.00417768164f);
    p = fmaf(p, ww, S * 0.246640727f);
    p = fmaf(p, ww, S * 1.50140941f);
  } else {
    float ww = __builtin_amdgcn_sqrtf(w) - 3.0f;
    p = S * -0.000200214257f;
    p = fmaf(p, ww, S * 0.000100950558f);
    p = fmaf(p, ww, S * 0.00134934322f);
    p = fmaf(p, ww, S * -0.00367342844f);
    p = fmaf(p, ww, S * 0.00573950773f);
    p = fmaf(p, ww, S * -0.0076224613f);
    p = fmaf(p, ww, S * 0.00943887047f);
    p = fmaf(p, ww, S * 1.00167406f);
    p = fmaf(p, ww, S * 2.83297682f);
  }
  return p * u;
}

// ---------- prep: LDS-tiled transposes into interleaved (mu,std) + biases ----------
__global__ __launch_bounds__(256) void prep_kernel(
    const float* __restrict__ x,
    const float* __restrict__ muW1, const float* __restrict__ vW1,
    const float* __restrict__ muW2, const float* __restrict__ vW2,
    const float* __restrict__ mub1, const float* __restrict__ vb1,
    const float* __restrict__ mub2, const float* __restrict__ vb2,
    float* __restrict__ ws,
    uint32_t kb1_0, uint32_t kb1_1, uint32_t kb2_0, uint32_t kb2_1) {
  __shared__ float2 tl[32][33];
  int bb = blockIdx.x;
  int tx = threadIdx.x & 31;
  int ty = threadIdx.x >> 5;        // 0..7

  if (bb < 512) {                   // W1 tile
    int i0 = (bb & 31) * 32, h0 = (bb >> 5) * 32;
#pragma unroll
    for (int r = 0; r < 4; ++r) {
      int h = h0 + ty + r * 8, i = i0 + tx;
      float m = muW1[h * D_IN + i];
      float s = expf(vW1[h * D_IN + i]);
      tl[ty + r * 8][tx] = make_float2(m, s);
    }
    __syncthreads();
    float2* ms1 = (float2*)(ws + OFF_MS1);
#pragma unroll
    for (int r = 0; r < 4; ++r) {
      int i = i0 + ty + r * 8, h = h0 + tx;
      ms1[i * D_H + h] = tl[tx][ty + r * 8];
    }
  } else if (bb < 640) {            // W2 tile
    int t = bb - 512;
    int h0 = (t & 15) * 32, o0 = (t >> 4) * 32;
#pragma unroll
    for (int r = 0; r < 4; ++r) {
      int o = o0 + ty + r * 8, hh = h0 + tx;
      float m = muW2[o * D_H + hh];
      float s = expf(vW2[o * D_H + hh]);
      tl[ty + r * 8][tx] = make_float2(m, s);
    }
    __syncthreads();
    float2* ms2 = (float2*)(ws + OFF_MS2);
#pragma unroll
    for (int r = 0; r < 4; ++r) {
      int hh = h0 + ty + r * 8, o = o0 + tx;
      ms2[hh * D_OUT + o] = tl[tx][ty + r * 8];
    }
  } else if (bb < 672) {            // xT tile
    int i0 = (bb - 640) * 32;
#pragma unroll
    for (int r = 0; r < 4; ++r) {
      int b = ty + r * 8, i = i0 + tx;
      tl[ty + r * 8][tx].x = x[b * D_IN + i];
    }
    __syncthreads();
#pragma unroll
    for (int r = 0; r < 4; ++r) {
      int i = i0 + ty + r * 8, b = tx;
      ws[OFF_XT + i * BATCH + b] = tl[tx][ty + r * 8].x;
    }
  } else if (bb < 747) {            // b1s
    int t0 = (bb - 672) * 1024 + threadIdx.x;
#pragma unroll
    for (int r = 0; r < 4; ++r) {
      int t = t0 + r * 256;
      int h = t & 511;
      float eps = tf_normal(kb1_0, kb1_1, (uint32_t)t);
      ws[OFF_B1S + t] = fmaf(eps, expf(vb1[h]), mub1[h]);
    }
  } else {                          // b2s
    int t0 = (bb - 747) * 1024 + threadIdx.x;
#pragma unroll
    for (int r = 0; r < 4; ++r) {
      int t = t0 + r * 256;
      if (t < NS * D_OUT) {
        int o = t & 255;
        float eps = tf_normal(kb2_0, kb2_1, (uint32_t)t);
        ws[OFF_B2S + t] = fmaf(eps, expf(vb2[o]), mub2[o]);
      }
    }
  }
}

// ---------- layer 1 ----------
// 256-thr blocks (4 waves): thread = (chunk c = t>>5 in 0..7, pair = t&31).
// Group = 32 consecutive (n,h) pairs; 2400 groups; grid = 2048 (8 blocks/CU
// via the 32-wave cap; LDS 8 KB, VGPR ~40 are not binding), grid-stride.
// NOTE: NO min-waves arg in __launch_bounds__ — (256,8) made the allocator
// target 32 VGPRs and spill the 32-float acc to scratch (R7: 12.9 GB HBM
// traffic, 3.1 ms). Bare bounds (R6) allocates ~36 VGPRs, no spill.
#define L1_GROUPS 2400
#define L1_GRID   2048
__global__ __launch_bounds__(256) void l1_kernel(
    const float* __restrict__ ws, float* __restrict__ hT,
    uint32_t k0, uint32_t k1) {
  const float* __restrict__ xT = ws + OFF_XT;
  const float2* __restrict__ ms1 = (const float2*)(ws + OFF_MS1);
  const float* __restrict__ b1s = ws + OFF_B1S;

  __shared__ float red[8][8][32];    // 8192 B; [chunk][b-slice][pair]

  int pair = threadIdx.x & 31;
  int c = threadIdx.x >> 5;          // 0..7 (half-wave uniform)

  for (int g = blockIdx.x; g < L1_GROUPS; g += L1_GRID) {
    int gid = g * 32 + pair;         // (n*512 + h)
    int h = gid & 511;

    float acc[BATCH];
#pragma unroll
    for (int b = 0; b < BATCH; ++b) acc[b] = 0.0f;

    uint32_t base = ((uint32_t)gid << 10) + (uint32_t)(c * 128);
    int i0 = c * 128;
#pragma unroll 4
    for (int ii = 0; ii < 128; ++ii) {
      int i = i0 + ii;
      float2 ms = ms1[i * D_H + h];             // half-wave 256B segments
      float eps = tf_normal(k0, k1, base + (uint32_t)ii);
      float wval = fmaf(eps, ms.y, ms.x);
      const float4* xp = (const float4*)(xT + i * BATCH);  // half-wave uniform
#pragma unroll
      for (int b4 = 0; b4 < 8; ++b4) {
        float4 xv = xp[b4];
        acc[b4 * 4 + 0] = fmaf(wval, xv.x, acc[b4 * 4 + 0]);
        acc[b4 * 4 + 1] = fmaf(wval, xv.y, acc[b4 * 4 + 1]);
        acc[b4 * 4 + 2] = fmaf(wval, xv.z, acc[b4 * 4 + 2]);
        acc[b4 * 4 + 3] = fmaf(wval, xv.w, acc[b4 * 4 + 3]);
      }
    }

    float bb = b1s[gid];
#pragma unroll
    for (int p4 = 0; p4 < 4; ++p4) {
#pragma unroll
      for (int j = 0; j < 8; ++j) red[c][j][pair] = acc[p4 * 8 + j];
      __syncthreads();
      // thread (c,pair) reduces output (gid(pair), b = p4*8 + c)
      float s = red[0][c][pair] + red[1][c][pair] + red[2][c][pair] + red[3][c][pair]
              + red[4][c][pair] + red[5][c][pair] + red[6][c][pair] + red[7][c][pair];
      hT[(size_t)gid * BATCH + p4 * 8 + c] = fmaxf(s + bb, 0.0f);
      __syncthreads();
    }
  }
}

// ---------- layer 2 ----------
// Same template: 256-thr blocks, 32 (n,o) pairs/group, 8 hh-chunks of 64.
// 1200 groups, grid = 1200 (< 2048 residency cap -> all resident, no tail).
__global__ __launch_bounds__(256) void l2_kernel(
    const float* __restrict__ ws, float* __restrict__ y,
    uint32_t k0, uint32_t k1) {
  const float* __restrict__ hT = ws + OFF_HT;
  const float2* __restrict__ ms2 = (const float2*)(ws + OFF_MS2);
  const float* __restrict__ b2s = ws + OFF_B2S;

  __shared__ float red[8][8][32];    // 8192 B

  int pair = threadIdx.x & 31;
  int c = threadIdx.x >> 5;          // 0..7
  int g = blockIdx.x;
  int gid = g * 32 + pair;           // (n*256 + o)
  int n = __builtin_amdgcn_readfirstlane(gid >> 8);  // uniform: 32 | 256
  int o = gid & 255;

  float acc[BATCH];
#pragma unroll
  for (int b = 0; b < BATCH; ++b) acc[b] = 0.0f;

  uint32_t base = ((uint32_t)gid << 9) + (uint32_t)(c * 64);
  int h0 = c * 64;
  const float* hbase = hT + (size_t)n * (D_H * BATCH);
#pragma unroll 4
  for (int jj = 0; jj < 64; ++jj) {
    int hh = h0 + jj;
    float2 ms = ms2[hh * D_OUT + o];            // half-wave 256B segments
    float eps = tf_normal(k0, k1, base + (uint32_t)jj);
    float wval = fmaf(eps, ms.y, ms.x);
    const float4* hp = (const float4*)(hbase + hh * BATCH);  // half-wave uniform
#pragma unroll
    for (int b4 = 0; b4 < 8; ++b4) {
      float4 hv = hp[b4];
      acc[b4 * 4 + 0] = fmaf(wval, hv.x, acc[b4 * 4 + 0]);
      acc[b4 * 4 + 1] = fmaf(wval, hv.y, acc[b4 * 4 + 1]);
      acc[b4 * 4 + 2] = fmaf(wval, hv.z, acc[b4 * 4 + 2]);
      acc[b4 * 4 + 3] = fmaf(wval, hv.w, acc[b4 * 4 + 3]);
    }
  }

  float bb = b2s[gid];
#pragma unroll
  for (int p4 = 0; p4 < 4; ++p4) {
#pragma unroll
    for (int j = 0; j < 8; ++j) red[c][j][pair] = acc[p4 * 8 + j];
    __syncthreads();
    float s = red[0][c][pair] + red[1][c][pair] + red[2][c][pair] + red[3][c][pair]
            + red[4][c][pair] + red[5][c][pair] + red[6][c][pair] + red[7][c][pair];
    int b = p4 * 8 + c;
    y[(size_t)n * (BATCH * D_OUT) + b * D_OUT + o] = s + bb;  // o inner: coalesced
    __syncthreads();
  }
}

extern "C" void kernel_launch(void* const* d_in, const int* in_sizes, int n_in,
                              void* d_out, int out_size, void* d_ws, size_t ws_size,
                              hipStream_t stream) {
  const float* x = (const float*)d_in[0];
  const float* muW1 = (const float*)d_in[1];
  const float* mub1 = (const float*)d_in[2];
  const float* muW2 = (const float*)d_in[3];
  const float* mub2 = (const float*)d_in[4];
  const float* vW1 = (const float*)d_in[5];
  const float* vb1 = (const float*)d_in[6];
  const float* vW2 = (const float*)d_in[7];
  const float* vb2 = (const float*)d_in[8];
  float* y = (float*)d_out;
  float* ws = (float*)d_ws;

  uint32_t nk[4][2];
  for (uint32_t j = 0; j < 4; ++j) {
    threefry2x32(0u, 42u, 0u, j, nk[j][0], nk[j][1]);
  }
  // eW1=nk[0], eb1=nk[1], eW2=nk[2], eb2=nk[3]

  prep_kernel<<<785, 256, 0, stream>>>(
      x, muW1, vW1, muW2, vW2, mub1, vb1, mub2, vb2, ws,
      nk[1][0], nk[1][1], nk[3][0], nk[3][1]);

  // l1: 2400 groups of 32 pairs, grid = 2048 (exact residency), stride loop
  l1_kernel<<<L1_GRID, 256, 0, stream>>>(ws, ws + OFF_HT, nk[0][0], nk[0][1]);

  // l2: 1200 groups of 32 pairs, all resident
  l2_kernel<<<NS * D_OUT / 32, 256, 0, stream>>>(ws, y, nk[2][0], nk[2][1]);
}

// Round 9
// 372.337 us; speedup vs baseline: 9.4967x; 1.3685x over previous
//
#include <hip/hip_runtime.h>
#include <stdint.h>

#define NS 150
#define D_IN 1024
#define D_H 512
#define D_OUT 256

typedef __bf16 bf16x8 __attribute__((ext_vector_type(8)));
typedef float f32x4 __attribute__((ext_vector_type(4)));

// ---- workspace layout (float offsets) ----
#define OFF_XF    0u          // x fragments, 32768 bf16 = 16384 floats (64 KB)
#define OFF_MS1T  16384u      // float2[512*1024] (mu,std) at [h][i] (natural layout)
#define OFF_MS2T  1064960u    // float2[256*512]  (mu,std) at [o][h]
#define OFF_B1S   1327104u    // 150*512 = 76800
#define OFF_B2S   1403904u    // 150*256 = 38400
#define OFF_HB    1442304u    // h bf16 [n][b][h]: 150*32*512 = 2457600 bf16 = 1228800 floats
// total 2,671,104 floats = 10.7 MB

// ---------- threefry-2x32 (JAX-exact, 20 rounds) ----------
#define ROTL32(x, r) __builtin_rotateleft32((x), (r))

__host__ __device__ __forceinline__ void threefry2x32(uint32_t k0, uint32_t k1,
                                                      uint32_t x0, uint32_t x1,
                                                      uint32_t& o0, uint32_t& o1) {
  uint32_t k2 = k0 ^ k1 ^ 0x1BD11BDAu;
  x0 += k0; x1 += k1;
#define TFR(r) { x0 += x1; x1 = ROTL32(x1, r); x1 ^= x0; }
  TFR(13) TFR(15) TFR(26) TFR(6)
  x0 += k1; x1 += k2 + 1u;
  TFR(17) TFR(29) TFR(16) TFR(24)
  x0 += k2; x1 += k0 + 2u;
  TFR(13) TFR(15) TFR(26) TFR(6)
  x0 += k0; x1 += k1 + 3u;
  TFR(17) TFR(29) TFR(16) TFR(24)
  x0 += k1; x1 += k2 + 4u;
  TFR(13) TFR(15) TFR(26) TFR(6)
  x0 += k2; x1 += k0 + 5u;
#undef TFR
  o0 = x0; o1 = x1;
}

// bits -> uniform(-1,1) -> sqrt2*erfinv; native log/sqrt; sqrt2 folded in coeffs.
__device__ __forceinline__ float tf_normal(uint32_t k0, uint32_t k1, uint32_t idx) {
  uint32_t o0, o1;
  threefry2x32(k0, k1, 0u, idx, o0, o1);
  uint32_t bits = o0 ^ o1;
  uint32_t fb = (bits >> 9) | 0x3F800000u;
  float m = __uint_as_float(fb);                 // [1,2)
  const float lo = -0.99999994f;                 // nextafter(-1,0)
  float u = fmaxf(fmaf(m, 2.0f, -3.0f), lo);
  float t = fmaf(u, -u, 1.0f);                   // 1-u^2, single rounding
  float w = -0.69314718056f * __builtin_amdgcn_logf(t);   // -ln(1-u^2)
  const float S = 1.41421354f;
  float p;
  if (w < 5.0f) {
    float ww = w - 2.5f;
    p = S * 2.81022636e-08f;
    p = fmaf(p, ww, S * 3.43273939e-07f);
    p = fmaf(p, ww, S * -3.5233877e-06f);
    p = fmaf(p, ww, S * -4.39150654e-06f);
    p = fmaf(p, ww, S * 0.00021858087f);
    p = fmaf(p, ww, S * -0.00125372503f);
    p = fmaf(p, ww, S * -0.00417768164f);
    p = fmaf(p, ww, S * 0.246640727f);
    p = fmaf(p, ww, S * 1.50140941f);
  } else {
    float ww = __builtin_amdgcn_sqrtf(w) - 3.0f;
    p = S * -0.000200214257f;
    p = fmaf(p, ww, S * 0.000100950558f);
    p = fmaf(p, ww, S * 0.00134934322f);
    p = fmaf(p, ww, S * -0.00367342844f);
    p = fmaf(p, ww, S * 0.00573950773f);
    p = fmaf(p, ww, S * -0.0076224613f);
    p = fmaf(p, ww, S * 0.00943887047f);
    p = fmaf(p, ww, S * 1.00167406f);
    p = fmaf(p, ww, S * 2.83297682f);
  }
  return p * u;
}

// ---------- prep ----------
// blocks 0..2047    : ms1T  (muW1,vW1 are already [h][i] -> interleave, no transpose)
// blocks 2048..2559 : ms2T  ([o][h], natural)
// blocks 2560..2687 : x fragments in exact MFMA B-operand order (bf16)
// blocks 2688..2987 : b1s sampled biases
// blocks 2988..3137 : b2s
__global__ __launch_bounds__(256) void prep_kernel(
    const float* __restrict__ x,
    const float* __restrict__ muW1, const float* __restrict__ vW1,
    const float* __restrict__ muW2, const float* __restrict__ vW2,
    const float* __restrict__ mub1, const float* __restrict__ vb1,
    const float* __restrict__ mub2, const float* __restrict__ vb2,
    float* __restrict__ ws,
    uint32_t kb1_0, uint32_t kb1_1, uint32_t kb2_0, uint32_t kb2_1) {
  int bb = blockIdx.x;
  int tid = threadIdx.x;
  if (bb < 2048) {
    int t = bb * 256 + tid;                       // 0..524287  ([h][i] flat)
    ((float2*)(ws + OFF_MS1T))[t] = make_float2(muW1[t], expf(vW1[t]));
  } else if (bb < 2560) {
    int t = (bb - 2048) * 256 + tid;              // 0..131071  ([o][h] flat)
    ((float2*)(ws + OFF_MS2T))[t] = make_float2(muW2[t], expf(vW2[t]));
  } else if (bb < 2688) {
    int t = (bb - 2560) * 256 + tid;              // 0..32767
    int j = t & 7, lane = (t >> 3) & 63, fidx = t >> 9;  // fidx = s*2+f
    int s = fidx >> 1, f = fidx & 1;
    int b = f * 16 + (lane & 15);
    int k = s * 32 + ((lane >> 4) << 3) + j;
    ((__bf16*)(ws + OFF_XF))[t] = (__bf16)x[b * D_IN + k];
  } else if (bb < 2988) {
    int t = (bb - 2688) * 256 + tid;              // 0..76799
    int h = t & 511;
    float eps = tf_normal(kb1_0, kb1_1, (uint32_t)t);
    ws[OFF_B1S + t] = fmaf(eps, expf(vb1[h]), mub1[h]);
  } else {
    int t = (bb - 2988) * 256 + tid;              // 0..38399
    int o = t & 255;
    float eps = tf_normal(kb2_0, kb2_1, (uint32_t)t);
    ws[OFF_B2S + t] = fmaf(eps, expf(vb2[o]), mub2[o]);
  }
}

// ---------- layer 1: one wave per (n, 16-h tile), full 32-batch via 2 MFMA tiles.
// A-frag (weights) generated in-registers: lane holds A[m=lane&15][k=quad*8+j],
// 8 independent threefry chains per lane per k-step (ILP). B-frag (x, bf16)
// pre-packed by prep in operand order -> one coalesced 16B load per tile.
// No LDS, no barriers, waves independent. 1200 blocks x 256 all-resident. ----------
__global__ __launch_bounds__(256) void l1_kernel(
    const float* __restrict__ ws, uint32_t k0, uint32_t k1) {
  const float2* __restrict__ ms1 = (const float2*)(ws + OFF_MS1T);
  const bf16x8* __restrict__ xf = (const bf16x8*)(ws + OFF_XF);
  const float* __restrict__ b1s = ws + OFF_B1S;
  __bf16* __restrict__ hB = (__bf16*)(ws + OFF_HB);

  int wave = blockIdx.x * 4 + (threadIdx.x >> 6);  // 0..4799
  int lane = threadIdx.x & 63;
  int n = wave >> 5;                 // sample
  int ht = wave & 31;                // h-tile
  int mrow = lane & 15, quad = lane >> 4;
  int h = ht * 16 + mrow;
  uint32_t base = ((uint32_t)(n * 512 + h)) << 10;   // eW1 flat base for (n,h)
  const float2* __restrict__ msrow = ms1 + (size_t)h * D_IN;

  f32x4 acc0 = {0.f, 0.f, 0.f, 0.f}, acc1 = {0.f, 0.f, 0.f, 0.f};

  for (int s = 0; s < 32; ++s) {
    int kq = s * 32 + quad * 8;
    const f32x4* msq = (const f32x4*)(msrow + kq);   // 8 float2 = 4 x 16B
    f32x4 q0 = msq[0], q1 = msq[1], q2 = msq[2], q3 = msq[3];
    float mu[8], sd[8];
    mu[0]=q0[0]; sd[0]=q0[1]; mu[1]=q0[2]; sd[1]=q0[3];
    mu[2]=q1[0]; sd[2]=q1[1]; mu[3]=q1[2]; sd[3]=q1[3];
    mu[4]=q2[0]; sd[4]=q2[1]; mu[5]=q2[2]; sd[5]=q2[3];
    mu[6]=q3[0]; sd[6]=q3[1]; mu[7]=q3[2]; sd[7]=q3[3];
    uint32_t kbase = base + (uint32_t)kq;
    bf16x8 a;
#pragma unroll
    for (int j = 0; j < 8; ++j) {
      float eps = tf_normal(k0, k1, kbase + (uint32_t)j);
      a[j] = (__bf16)fmaf(eps, sd[j], mu[j]);
    }
    bf16x8 b0 = xf[(s * 2 + 0) * 64 + lane];
    bf16x8 b1 = xf[(s * 2 + 1) * 64 + lane];
    acc0 = __builtin_amdgcn_mfma_f32_16x16x32_bf16(a, b0, acc0, 0, 0, 0);
    acc1 = __builtin_amdgcn_mfma_f32_16x16x32_bf16(a, b1, acc1, 0, 0, 0);
  }

  // epilogue: D col=lane&15 (b within half), row=quad*4+r (h within tile)
  int hq = ht * 16 + quad * 4;
  const float* bp = b1s + n * 512 + hq;
  float4 bias = *(const float4*)bp;
  union { __bf16 v[4]; uint2 u; } p0, p1;
  float bv[4] = {bias.x, bias.y, bias.z, bias.w};
#pragma unroll
  for (int r = 0; r < 4; ++r) {
    p0.v[r] = (__bf16)fmaxf(acc0[r] + bv[r], 0.0f);
    p1.v[r] = (__bf16)fmaxf(acc1[r] + bv[r], 0.0f);
  }
  *(uint2*)(hB + ((size_t)(n * 32 + mrow) * 512 + hq)) = p0.u;        // b = mrow
  *(uint2*)(hB + ((size_t)(n * 32 + 16 + mrow) * 512 + hq)) = p1.u;   // b = 16+mrow
}

// ---------- layer 2: one wave per (n, 16-o tile); K = 512 (h), h from hB (bf16). ----------
__global__ __launch_bounds__(256) void l2_kernel(
    const float* __restrict__ ws, float* __restrict__ y,
    uint32_t k0, uint32_t k1) {
  const float2* __restrict__ ms2 = (const float2*)(ws + OFF_MS2T);
  const bf16x8* __restrict__ hB8 = (const bf16x8*)(ws + OFF_HB);
  const float* __restrict__ b2s = ws + OFF_B2S;

  int wave = blockIdx.x * 4 + (threadIdx.x >> 6);  // 0..2399
  int lane = threadIdx.x & 63;
  int n = wave >> 4;                 // sample
  int ot = wave & 15;                // o-tile
  int mrow = lane & 15, quad = lane >> 4;
  int o = ot * 16 + mrow;
  uint32_t base = (uint32_t)(n * 256 + o) << 9;    // eW2 flat base for (n,o)
  const float2* __restrict__ msrow = ms2 + (size_t)o * D_H;

  f32x4 acc0 = {0.f, 0.f, 0.f, 0.f}, acc1 = {0.f, 0.f, 0.f, 0.f};

  for (int s = 0; s < 16; ++s) {
    int kq = s * 32 + quad * 8;
    const f32x4* msq = (const f32x4*)(msrow + kq);
    f32x4 q0 = msq[0], q1 = msq[1], q2 = msq[2], q3 = msq[3];
    float mu[8], sd[8];
    mu[0]=q0[0]; sd[0]=q0[1]; mu[1]=q0[2]; sd[1]=q0[3];
    mu[2]=q1[0]; sd[2]=q1[1]; mu[3]=q1[2]; sd[3]=q1[3];
    mu[4]=q2[0]; sd[4]=q2[1]; mu[5]=q2[2]; sd[5]=q2[3];
    mu[6]=q3[0]; sd[6]=q3[1]; mu[7]=q3[2]; sd[7]=q3[3];
    uint32_t kbase = base + (uint32_t)kq;
    bf16x8 a;
#pragma unroll
    for (int j = 0; j < 8; ++j) {
      float eps = tf_normal(k0, k1, kbase + (uint32_t)j);
      a[j] = (__bf16)fmaf(eps, sd[j], mu[j]);
    }
    // B-frag: hB[n][b][h], lane: b = f*16 + mrow(col), h = kq..kq+7 consecutive
    bf16x8 b0 = hB8[(size_t)(n * 32 + mrow) * 64 + s * 4 + quad];
    bf16x8 b1 = hB8[(size_t)(n * 32 + 16 + mrow) * 64 + s * 4 + quad];
    acc0 = __builtin_amdgcn_mfma_f32_16x16x32_bf16(a, b0, acc0, 0, 0, 0);
    acc1 = __builtin_amdgcn_mfma_f32_16x16x32_bf16(a, b1, acc1, 0, 0, 0);
  }

  // epilogue: row = o within tile, col = b within half; y[n][b][o] fp32
  int oq = ot * 16 + quad * 4;
  float4 bias = *(const float4*)(b2s + n * 256 + oq);
  float4 o0, o1;
  o0.x = acc0[0] + bias.x; o0.y = acc0[1] + bias.y;
  o0.z = acc0[2] + bias.z; o0.w = acc0[3] + bias.w;
  o1.x = acc1[0] + bias.x; o1.y = acc1[1] + bias.y;
  o1.z = acc1[2] + bias.z; o1.w = acc1[3] + bias.w;
  *(float4*)(y + (size_t)(n * 32 + mrow) * 256 + oq) = o0;        // b = mrow
  *(float4*)(y + (size_t)(n * 32 + 16 + mrow) * 256 + oq) = o1;   // b = 16+mrow
}

extern "C" void kernel_launch(void* const* d_in, const int* in_sizes, int n_in,
                              void* d_out, int out_size, void* d_ws, size_t ws_size,
                              hipStream_t stream) {
  const float* x = (const float*)d_in[0];
  const float* muW1 = (const float*)d_in[1];
  const float* mub1 = (const float*)d_in[2];
  const float* muW2 = (const float*)d_in[3];
  const float* mub2 = (const float*)d_in[4];
  const float* vW1 = (const float*)d_in[5];
  const float* vb1 = (const float*)d_in[6];
  const float* vW2 = (const float*)d_in[7];
  const float* vb2 = (const float*)d_in[8];
  float* y = (float*)d_out;
  float* ws = (float*)d_ws;

  uint32_t nk[4][2];
  for (uint32_t j = 0; j < 4; ++j) {
    threefry2x32(0u, 42u, 0u, j, nk[j][0], nk[j][1]);
  }
  // eW1=nk[0], eb1=nk[1], eW2=nk[2], eb2=nk[3]

  prep_kernel<<<3138, 256, 0, stream>>>(
      x, muW1, vW1, muW2, vW2, mub1, vb1, mub2, vb2, ws,
      nk[1][0], nk[1][1], nk[3][0], nk[3][1]);

  // l1: 4800 waves (150 n x 32 h-tiles), 4 waves/block -> 1200 blocks
  l1_kernel<<<1200, 256, 0, stream>>>(ws, nk[0][0], nk[0][1]);

  // l2: 2400 waves (150 n x 16 o-tiles) -> 600 blocks
  l2_kernel<<<600, 256, 0, stream>>>(ws, y, nk[2][0], nk[2][1]);
}

// Round 10
// 349.092 us; speedup vs baseline: 10.1290x; 1.0666x over previous
//
#include <hip/hip_runtime.h>
#include <stdint.h>

#define NS 150
#define D_IN 1024
#define D_H 512
#define D_OUT 256

typedef __bf16 bf16x8 __attribute__((ext_vector_type(8)));
typedef float f32x4 __attribute__((ext_vector_type(4)));

// ---- workspace layout (float offsets) ----
#define OFF_XF    0u          // x fragments, 32768 bf16 (MFMA B-operand order)
#define OFF_MS1T  16384u      // float2[512*1024] (mu,std) at [h][i]
#define OFF_MS2T  1064960u    // float2[256*512]  (mu,std) at [o][h]
#define OFF_B1S   1327104u    // 150*512 = 76800
#define OFF_B2S   1403904u    // 150*256 = 38400
#define OFF_HB    1442304u    // h bf16 [n][b][h]: 150*32*512 bf16

// ---------- threefry-2x32 (JAX-exact, 20 rounds) ----------
#define ROTL32(x, r) __builtin_rotateleft32((x), (r))

__host__ __device__ __forceinline__ void threefry2x32(uint32_t k0, uint32_t k1,
                                                      uint32_t x0, uint32_t x1,
                                                      uint32_t& o0, uint32_t& o1) {
  uint32_t k2 = k0 ^ k1 ^ 0x1BD11BDAu;
  x0 += k0; x1 += k1;
#define TFR(r) { x0 += x1; x1 = ROTL32(x1, r); x1 ^= x0; }
  TFR(13) TFR(15) TFR(26) TFR(6)
  x0 += k1; x1 += k2 + 1u;
  TFR(17) TFR(29) TFR(16) TFR(24)
  x0 += k2; x1 += k0 + 2u;
  TFR(13) TFR(15) TFR(26) TFR(6)
  x0 += k0; x1 += k1 + 3u;
  TFR(17) TFR(29) TFR(16) TFR(24)
  x0 += k1; x1 += k2 + 4u;
  TFR(13) TFR(15) TFR(26) TFR(6)
  x0 += k2; x1 += k0 + 5u;
#undef TFR
  o0 = x0; o1 = x1;
}

// bits -> uniform(-1,1) -> sqrt2*erfinv; native log/sqrt; sqrt2 folded in coeffs.
__device__ __forceinline__ float tf_normal(uint32_t k0, uint32_t k1, uint32_t idx) {
  uint32_t o0, o1;
  threefry2x32(k0, k1, 0u, idx, o0, o1);
  uint32_t bits = o0 ^ o1;
  uint32_t fb = (bits >> 9) | 0x3F800000u;
  float m = __uint_as_float(fb);                 // [1,2)
  const float lo = -0.99999994f;                 // nextafter(-1,0)
  float u = fmaxf(fmaf(m, 2.0f, -3.0f), lo);
  float t = fmaf(u, -u, 1.0f);                   // 1-u^2, single rounding
  float w = -0.69314718056f * __builtin_amdgcn_logf(t);   // -ln(1-u^2)
  const float S = 1.41421354f;
  float p;
  if (w < 5.0f) {
    float ww = w - 2.5f;
    p = S * 2.81022636e-08f;
    p = fmaf(p, ww, S * 3.43273939e-07f);
    p = fmaf(p, ww, S * -3.5233877e-06f);
    p = fmaf(p, ww, S * -4.39150654e-06f);
    p = fmaf(p, ww, S * 0.00021858087f);
    p = fmaf(p, ww, S * -0.00125372503f);
    p = fmaf(p, ww, S * -0.00417768164f);
    p = fmaf(p, ww, S * 0.246640727f);
    p = fmaf(p, ww, S * 1.50140941f);
  } else {
    float ww = __builtin_amdgcn_sqrtf(w) - 3.0f;
    p = S * -0.000200214257f;
    p = fmaf(p, ww, S * 0.000100950558f);
    p = fmaf(p, ww, S * 0.00134934322f);
    p = fmaf(p, ww, S * -0.00367342844f);
    p = fmaf(p, ww, S * 0.00573950773f);
    p = fmaf(p, ww, S * -0.0076224613f);
    p = fmaf(p, ww, S * 0.00943887047f);
    p = fmaf(p, ww, S * 1.00167406f);
    p = fmaf(p, ww, S * 2.83297682f);
  }
  return p * u;
}

// ---------- prep ----------
__global__ __launch_bounds__(256) void prep_kernel(
    const float* __restrict__ x,
    const float* __restrict__ muW1, const float* __restrict__ vW1,
    const float* __restrict__ muW2, const float* __restrict__ vW2,
    const float* __restrict__ mub1, const float* __restrict__ vb1,
    const float* __restrict__ mub2, const float* __restrict__ vb2,
    float* __restrict__ ws,
    uint32_t kb1_0, uint32_t kb1_1, uint32_t kb2_0, uint32_t kb2_1) {
  int bb = blockIdx.x;
  int tid = threadIdx.x;
  if (bb < 2048) {
    int t = bb * 256 + tid;                       // [h][i] flat
    ((float2*)(ws + OFF_MS1T))[t] = make_float2(muW1[t], expf(vW1[t]));
  } else if (bb < 2560) {
    int t = (bb - 2048) * 256 + tid;              // [o][h] flat
    ((float2*)(ws + OFF_MS2T))[t] = make_float2(muW2[t], expf(vW2[t]));
  } else if (bb < 2688) {
    int t = (bb - 2560) * 256 + tid;              // x fragments, B-operand order
    int j = t & 7, lane = (t >> 3) & 63, fidx = t >> 9;
    int s = fidx >> 1, f = fidx & 1;
    int b = f * 16 + (lane & 15);
    int k = s * 32 + ((lane >> 4) << 3) + j;
    ((__bf16*)(ws + OFF_XF))[t] = (__bf16)x[b * D_IN + k];
  } else if (bb < 2988) {
    int t = (bb - 2688) * 256 + tid;              // b1s
    int h = t & 511;
    float eps = tf_normal(kb1_0, kb1_1, (uint32_t)t);
    ws[OFF_B1S + t] = fmaf(eps, expf(vb1[h]), mub1[h]);
  } else {
    int t = (bb - 2988) * 256 + tid;              // b2s
    int o = t & 255;
    float eps = tf_normal(kb2_0, kb2_1, (uint32_t)t);
    ws[OFF_B2S + t] = fmaf(eps, expf(vb2[o]), mub2[o]);
  }
}

// ---------- layer 1 ----------
// K-split 2: wave-unit = (tile, khalf); tile = (n, 16-h); each wave does 16
// of the 32 k-steps. 9600 waves (was 4800 = 58% max occupancy, measured 33%).
// Block = 2 tiles x 2 khalves; khalf=1 dumps partial accs to LDS (4 KB),
// khalf=0 adds + epilogue. A-frags RNG'd in-registers (8 indep chains/lane),
// B-frags pre-packed. No min-waves hints (R7: (256,8) -> spill disaster).
__global__ __launch_bounds__(256) void l1_kernel(
    const float* __restrict__ ws, uint32_t k0, uint32_t k1) {
  const float2* __restrict__ ms1 = (const float2*)(ws + OFF_MS1T);
  const bf16x8* __restrict__ xf = (const bf16x8*)(ws + OFF_XF);
  const float* __restrict__ b1s = ws + OFF_B1S;
  __bf16* __restrict__ hB = (__bf16*)(ws + OFF_HB);

  __shared__ f32x4 lred[2][2][64];   // [pair][acc][lane] = 4096 B

  int lane = threadIdx.x & 63;
  int wib = threadIdx.x >> 6;        // 0..3
  int pairIdx = wib >> 1, khalf = wib & 1;
  int tile = blockIdx.x * 2 + pairIdx;   // 0..4799
  int n = tile >> 5;                 // sample
  int ht = tile & 31;                // h-tile
  int mrow = lane & 15, quad = lane >> 4;
  int h = ht * 16 + mrow;
  uint32_t base = ((uint32_t)(n * 512 + h)) << 10;
  const float2* __restrict__ msrow = ms1 + (size_t)h * D_IN;

  f32x4 acc0 = {0.f, 0.f, 0.f, 0.f}, acc1 = {0.f, 0.f, 0.f, 0.f};

  int send = khalf * 16 + 16;
  for (int s = khalf * 16; s < send; ++s) {
    int kq = s * 32 + quad * 8;
    const f32x4* msq = (const f32x4*)(msrow + kq);
    f32x4 q0 = msq[0], q1 = msq[1], q2 = msq[2], q3 = msq[3];
    float mu[8], sd[8];
    mu[0]=q0[0]; sd[0]=q0[1]; mu[1]=q0[2]; sd[1]=q0[3];
    mu[2]=q1[0]; sd[2]=q1[1]; mu[3]=q1[2]; sd[3]=q1[3];
    mu[4]=q2[0]; sd[4]=q2[1]; mu[5]=q2[2]; sd[5]=q2[3];
    mu[6]=q3[0]; sd[6]=q3[1]; mu[7]=q3[2]; sd[7]=q3[3];
    uint32_t kbase = base + (uint32_t)kq;
    bf16x8 a;
#pragma unroll
    for (int j = 0; j < 8; ++j) {
      float eps = tf_normal(k0, k1, kbase + (uint32_t)j);
      a[j] = (__bf16)fmaf(eps, sd[j], mu[j]);
    }
    bf16x8 b0 = xf[(s * 2 + 0) * 64 + lane];
    bf16x8 b1 = xf[(s * 2 + 1) * 64 + lane];
    acc0 = __builtin_amdgcn_mfma_f32_16x16x32_bf16(a, b0, acc0, 0, 0, 0);
    acc1 = __builtin_amdgcn_mfma_f32_16x16x32_bf16(a, b1, acc1, 0, 0, 0);
  }

  if (khalf) {
    lred[pairIdx][0][lane] = acc0;
    lred[pairIdx][1][lane] = acc1;
  }
  __syncthreads();
  if (!khalf) {
    f32x4 r0 = lred[pairIdx][0][lane], r1 = lred[pairIdx][1][lane];
    acc0 += r0; acc1 += r1;
    // D layout: col=lane&15 (b within half), row=quad*4+r (h within tile)
    int hq = ht * 16 + quad * 4;
    float4 bias = *(const float4*)(b1s + n * 512 + hq);
    float bv[4] = {bias.x, bias.y, bias.z, bias.w};
    union { __bf16 v[4]; uint2 u; } p0, p1;
#pragma unroll
    for (int r = 0; r < 4; ++r) {
      p0.v[r] = (__bf16)fmaxf(acc0[r] + bv[r], 0.0f);
      p1.v[r] = (__bf16)fmaxf(acc1[r] + bv[r], 0.0f);
    }
    *(uint2*)(hB + ((size_t)(n * 32 + mrow) * 512 + hq)) = p0.u;        // b = mrow
    *(uint2*)(hB + ((size_t)(n * 32 + 16 + mrow) * 512 + hq)) = p1.u;   // b = 16+mrow
  }
}

// ---------- layer 2 ----------
// K-split 4: block = 1 tile x 4 k-quarters (4 s-steps each); 9600 waves
// (was 2400 = 29% max occupancy). Waves 1-3 dump accs to LDS (6 KB),
// wave 0 adds + epilogue.
__global__ __launch_bounds__(256) void l2_kernel(
    const float* __restrict__ ws, float* __restrict__ y,
    uint32_t k0, uint32_t k1) {
  const float2* __restrict__ ms2 = (const float2*)(ws + OFF_MS2T);
  const bf16x8* __restrict__ hB8 = (const bf16x8*)(ws + OFF_HB);
  const float* __restrict__ b2s = ws + OFF_B2S;

  __shared__ f32x4 lred[3][2][64];   // 6144 B

  int lane = threadIdx.x & 63;
  int wib = threadIdx.x >> 6;        // k-quarter 0..3
  int tile = blockIdx.x;             // 0..2399
  int n = tile >> 4;                 // sample
  int ot = tile & 15;                // o-tile
  int mrow = lane & 15, quad = lane >> 4;
  int o = ot * 16 + mrow;
  uint32_t base = (uint32_t)(n * 256 + o) << 9;
  const float2* __restrict__ msrow = ms2 + (size_t)o * D_H;

  f32x4 acc0 = {0.f, 0.f, 0.f, 0.f}, acc1 = {0.f, 0.f, 0.f, 0.f};

  int send = wib * 4 + 4;
  for (int s = wib * 4; s < send; ++s) {
    int kq = s * 32 + quad * 8;
    const f32x4* msq = (const f32x4*)(msrow + kq);
    f32x4 q0 = msq[0], q1 = msq[1], q2 = msq[2], q3 = msq[3];
    float mu[8], sd[8];
    mu[0]=q0[0]; sd[0]=q0[1]; mu[1]=q0[2]; sd[1]=q0[3];
    mu[2]=q1[0]; sd[2]=q1[1]; mu[3]=q1[2]; sd[3]=q1[3];
    mu[4]=q2[0]; sd[4]=q2[1]; mu[5]=q2[2]; sd[5]=q2[3];
    mu[6]=q3[0]; sd[6]=q3[1]; mu[7]=q3[2]; sd[7]=q3[3];
    uint32_t kbase = base + (uint32_t)kq;
    bf16x8 a;
#pragma unroll
    for (int j = 0; j < 8; ++j) {
      float eps = tf_normal(k0, k1, kbase + (uint32_t)j);
      a[j] = (__bf16)fmaf(eps, sd[j], mu[j]);
    }
    bf16x8 b0 = hB8[(size_t)(n * 32 + mrow) * 64 + s * 4 + quad];
    bf16x8 b1 = hB8[(size_t)(n * 32 + 16 + mrow) * 64 + s * 4 + quad];
    acc0 = __builtin_amdgcn_mfma_f32_16x16x32_bf16(a, b0, acc0, 0, 0, 0);
    acc1 = __builtin_amdgcn_mfma_f32_16x16x32_bf16(a, b1, acc1, 0, 0, 0);
  }

  if (wib) {
    lred[wib - 1][0][lane] = acc0;
    lred[wib - 1][1][lane] = acc1;
  }
  __syncthreads();
  if (!wib) {
#pragma unroll
    for (int c = 0; c < 3; ++c) {
      acc0 += lred[c][0][lane];
      acc1 += lred[c][1][lane];
    }
    int oq = ot * 16 + quad * 4;
    float4 bias = *(const float4*)(b2s + n * 256 + oq);
    float4 o0, o1;
    o0.x = acc0[0] + bias.x; o0.y = acc0[1] + bias.y;
    o0.z = acc0[2] + bias.z; o0.w = acc0[3] + bias.w;
    o1.x = acc1[0] + bias.x; o1.y = acc1[1] + bias.y;
    o1.z = acc1[2] + bias.z; o1.w = acc1[3] + bias.w;
    *(float4*)(y + (size_t)(n * 32 + mrow) * 256 + oq) = o0;        // b = mrow
    *(float4*)(y + (size_t)(n * 32 + 16 + mrow) * 256 + oq) = o1;   // b = 16+mrow
  }
}

extern "C" void kernel_launch(void* const* d_in, const int* in_sizes, int n_in,
                              void* d_out, int out_size, void* d_ws, size_t ws_size,
                              hipStream_t stream) {
  const float* x = (const float*)d_in[0];
  const float* muW1 = (const float*)d_in[1];
  const float* mub1 = (const float*)d_in[2];
  const float* muW2 = (const float*)d_in[3];
  const float* mub2 = (const float*)d_in[4];
  const float* vW1 = (const float*)d_in[5];
  const float* vb1 = (const float*)d_in[6];
  const float* vW2 = (const float*)d_in[7];
  const float* vb2 = (const float*)d_in[8];
  float* y = (float*)d_out;
  float* ws = (float*)d_ws;

  uint32_t nk[4][2];
  for (uint32_t j = 0; j < 4; ++j) {
    threefry2x32(0u, 42u, 0u, j, nk[j][0], nk[j][1]);
  }
  // eW1=nk[0], eb1=nk[1], eW2=nk[2], eb2=nk[3]

  prep_kernel<<<3138, 256, 0, stream>>>(
      x, muW1, vW1, muW2, vW2, mub1, vb1, mub2, vb2, ws,
      nk[1][0], nk[1][1], nk[3][0], nk[3][1]);

  // l1: 4800 tiles x 2 k-halves = 9600 waves -> 2400 blocks x 256
  l1_kernel<<<2400, 256, 0, stream>>>(ws, nk[0][0], nk[0][1]);

  // l2: 2400 tiles x 4 k-quarters = 9600 waves -> 2400 blocks x 256
  l2_kernel<<<2400, 256, 0, stream>>>(ws, y, nk[2][0], nk[2][1]);
}

// Round 11
// 347.746 us; speedup vs baseline: 10.1682x; 1.0039x over previous
//
#include <hip/hip_runtime.h>
#include <stdint.h>

#define NS 150
#define D_IN 1024
#define D_H 512
#define D_OUT 256

typedef __bf16 bf16x8 __attribute__((ext_vector_type(8)));
typedef float f32x4 __attribute__((ext_vector_type(4)));

// ---- workspace layout (float offsets) ----
#define OFF_XF    0u          // x fragments, 32768 bf16 (MFMA B-operand order)
#define OFF_MS1T  16384u      // float2[512*1024] (mu,std) at [h][i]
#define OFF_MS2T  1064960u    // float2[256*512]  (mu,std) at [o][h]
#define OFF_B1S   1327104u    // 150*512 = 76800
#define OFF_B2S   1403904u    // 150*256 = 38400
#define OFF_HB    1442304u    // h bf16 [n][b][h]: 150*32*512 bf16

// ---------- threefry-2x32 (JAX-exact, 20 rounds) ----------
#define ROTL32(x, r) __builtin_rotateleft32((x), (r))

__host__ __device__ __forceinline__ void threefry2x32(uint32_t k0, uint32_t k1,
                                                      uint32_t x0, uint32_t x1,
                                                      uint32_t& o0, uint32_t& o1) {
  uint32_t k2 = k0 ^ k1 ^ 0x1BD11BDAu;
  x0 += k0; x1 += k1;
#define TFR(r) { x0 += x1; x1 = ROTL32(x1, r); x1 ^= x0; }
  TFR(13) TFR(15) TFR(26) TFR(6)
  x0 += k1; x1 += k2 + 1u;
  TFR(17) TFR(29) TFR(16) TFR(24)
  x0 += k2; x1 += k0 + 2u;
  TFR(13) TFR(15) TFR(26) TFR(6)
  x0 += k0; x1 += k1 + 3u;
  TFR(17) TFR(29) TFR(16) TFR(24)
  x0 += k1; x1 += k2 + 4u;
  TFR(13) TFR(15) TFR(26) TFR(6)
  x0 += k2; x1 += k0 + 5u;
#undef TFR
  o0 = x0; o1 = x1;
}

// scalar path (prep biases)
__device__ __forceinline__ float tf_normal(uint32_t k0, uint32_t k1, uint32_t idx) {
  uint32_t o0, o1;
  threefry2x32(k0, k1, 0u, idx, o0, o1);
  uint32_t bits = o0 ^ o1;
  uint32_t fb = (bits >> 9) | 0x3F800000u;
  float m = __uint_as_float(fb);
  const float lo = -0.99999994f;
  float u = fmaxf(fmaf(m, 2.0f, -3.0f), lo);
  float t = fmaf(u, -u, 1.0f);
  float w = -0.69314718056f * __builtin_amdgcn_logf(t);
  const float S = 1.41421354f;
  float p;
  if (w < 5.0f) {
    float ww = w - 2.5f;
    p = S * 2.81022636e-08f;
    p = fmaf(p, ww, S * 3.43273939e-07f);
    p = fmaf(p, ww, S * -3.5233877e-06f);
    p = fmaf(p, ww, S * -4.39150654e-06f);
    p = fmaf(p, ww, S * 0.00021858087f);
    p = fmaf(p, ww, S * -0.00125372503f);
    p = fmaf(p, ww, S * -0.00417768164f);
    p = fmaf(p, ww, S * 0.246640727f);
    p = fmaf(p, ww, S * 1.50140941f);
  } else {
    float ww = __builtin_amdgcn_sqrtf(w) - 3.0f;
    p = S * -0.000200214257f;
    p = fmaf(p, ww, S * 0.000100950558f);
    p = fmaf(p, ww, S * 0.00134934322f);
    p = fmaf(p, ww, S * -0.00367342844f);
    p = fmaf(p, ww, S * 0.00573950773f);
    p = fmaf(p, ww, S * -0.0076224613f);
    p = fmaf(p, ww, S * 0.00943887047f);
    p = fmaf(p, ww, S * 1.00167406f);
    p = fmaf(p, ww, S * 2.83297682f);
  }
  return p * u;
}

// ---------- 8-chain SoA threefry + normal transform ----------
// Round-major interleave: every round issues 3 ops x 8 INDEPENDENT chains.
// Forces ~16 live state regs + ILP=8 so the allocator cannot serialize the
// chains into a 36-VGPR shape (R9/R10: VGPR=36, ~240 emitted instr/elem vs
// ~95 static -- suspected serialization/remat bloat).
__device__ __forceinline__ void tf8_round(uint32_t* s0, uint32_t* s1, int r) {
#pragma unroll
  for (int j = 0; j < 8; ++j) {
    s0[j] += s1[j];
    s1[j] = ROTL32(s1[j], r);
    s1[j] ^= s0[j];
  }
}

__device__ __forceinline__ void tf8_inj(uint32_t* s0, uint32_t* s1,
                                        uint32_t ka, uint32_t kb) {
#pragma unroll
  for (int j = 0; j < 8; ++j) { s0[j] += ka; s1[j] += kb; }
}

__device__ __forceinline__ void tf_normal8(uint32_t k0, uint32_t k1, uint32_t k2,
                                           uint32_t idx0, float* eps) {
  uint32_t s0[8], s1[8];
  uint32_t t0 = idx0 + k1;
#pragma unroll
  for (int j = 0; j < 8; ++j) { s0[j] = k0; s1[j] = t0 + (uint32_t)j; }
  tf8_round(s0, s1, 13); tf8_round(s0, s1, 15);
  tf8_round(s0, s1, 26); tf8_round(s0, s1, 6);
  tf8_inj(s0, s1, k1, k2 + 1u);
  tf8_round(s0, s1, 17); tf8_round(s0, s1, 29);
  tf8_round(s0, s1, 16); tf8_round(s0, s1, 24);
  tf8_inj(s0, s1, k2, k0 + 2u);
  tf8_round(s0, s1, 13); tf8_round(s0, s1, 15);
  tf8_round(s0, s1, 26); tf8_round(s0, s1, 6);
  tf8_inj(s0, s1, k0, k1 + 3u);
  tf8_round(s0, s1, 17); tf8_round(s0, s1, 29);
  tf8_round(s0, s1, 16); tf8_round(s0, s1, 24);
  tf8_inj(s0, s1, k1, k2 + 4u);
  tf8_round(s0, s1, 13); tf8_round(s0, s1, 15);
  tf8_round(s0, s1, 26); tf8_round(s0, s1, 6);
  tf8_inj(s0, s1, k2, k0 + 5u);

  const float lo = -0.99999994f;
  const float S = 1.41421354f;
#pragma unroll
  for (int j = 0; j < 8; ++j) {
    uint32_t bits = s0[j] ^ s1[j];
    uint32_t fb = (bits >> 9) | 0x3F800000u;
    float m = __uint_as_float(fb);
    float u = fmaxf(fmaf(m, 2.0f, -3.0f), lo);
    float t = fmaf(u, -u, 1.0f);
    float w = -0.69314718056f * __builtin_amdgcn_logf(t);
    float p;
    if (w < 5.0f) {
      float ww = w - 2.5f;
      p = S * 2.81022636e-08f;
      p = fmaf(p, ww, S * 3.43273939e-07f);
      p = fmaf(p, ww, S * -3.5233877e-06f);
      p = fmaf(p, ww, S * -4.39150654e-06f);
      p = fmaf(p, ww, S * 0.00021858087f);
      p = fmaf(p, ww, S * -0.00125372503f);
      p = fmaf(p, ww, S * -0.00417768164f);
      p = fmaf(p, ww, S * 0.246640727f);
      p = fmaf(p, ww, S * 1.50140941f);
    } else {
      float ww = __builtin_amdgcn_sqrtf(w) - 3.0f;
      p = S * -0.000200214257f;
      p = fmaf(p, ww, S * 0.000100950558f);
      p = fmaf(p, ww, S * 0.00134934322f);
      p = fmaf(p, ww, S * -0.00367342844f);
      p = fmaf(p, ww, S * 0.00573950773f);
      p = fmaf(p, ww, S * -0.0076224613f);
      p = fmaf(p, ww, S * 0.00943887047f);
      p = fmaf(p, ww, S * 1.00167406f);
      p = fmaf(p, ww, S * 2.83297682f);
    }
    eps[j] = p * u;
  }
}

// ---------- prep ----------
__global__ __launch_bounds__(256) void prep_kernel(
    const float* __restrict__ x,
    const float* __restrict__ muW1, const float* __restrict__ vW1,
    const float* __restrict__ muW2, const float* __restrict__ vW2,
    const float* __restrict__ mub1, const float* __restrict__ vb1,
    const float* __restrict__ mub2, const float* __restrict__ vb2,
    float* __restrict__ ws,
    uint32_t kb1_0, uint32_t kb1_1, uint32_t kb2_0, uint32_t kb2_1) {
  int bb = blockIdx.x;
  int tid = threadIdx.x;
  if (bb < 2048) {
    int t = bb * 256 + tid;                       // [h][i] flat
    ((float2*)(ws + OFF_MS1T))[t] = make_float2(muW1[t], expf(vW1[t]));
  } else if (bb < 2560) {
    int t = (bb - 2048) * 256 + tid;              // [o][h] flat
    ((float2*)(ws + OFF_MS2T))[t] = make_float2(muW2[t], expf(vW2[t]));
  } else if (bb < 2688) {
    int t = (bb - 2560) * 256 + tid;              // x fragments, B-operand order
    int j = t & 7, lane = (t >> 3) & 63, fidx = t >> 9;
    int s = fidx >> 1, f = fidx & 1;
    int b = f * 16 + (lane & 15);
    int k = s * 32 + ((lane >> 4) << 3) + j;
    ((__bf16*)(ws + OFF_XF))[t] = (__bf16)x[b * D_IN + k];
  } else if (bb < 2988) {
    int t = (bb - 2688) * 256 + tid;              // b1s
    int h = t & 511;
    float eps = tf_normal(kb1_0, kb1_1, (uint32_t)t);
    ws[OFF_B1S + t] = fmaf(eps, expf(vb1[h]), mub1[h]);
  } else {
    int t = (bb - 2988) * 256 + tid;              // b2s
    int o = t & 255;
    float eps = tf_normal(kb2_0, kb2_1, (uint32_t)t);
    ws[OFF_B2S + t] = fmaf(eps, expf(vb2[o]), mub2[o]);
  }
}

// ---------- layer 1: K-split 2, 9600 waves; A-frags RNG'd via tf_normal8 ----------
__global__ __launch_bounds__(256) void l1_kernel(
    const float* __restrict__ ws, uint32_t k0, uint32_t k1) {
  const float2* __restrict__ ms1 = (const float2*)(ws + OFF_MS1T);
  const bf16x8* __restrict__ xf = (const bf16x8*)(ws + OFF_XF);
  const float* __restrict__ b1s = ws + OFF_B1S;
  __bf16* __restrict__ hB = (__bf16*)(ws + OFF_HB);
  uint32_t k2 = k0 ^ k1 ^ 0x1BD11BDAu;

  __shared__ f32x4 lred[2][2][64];   // 4096 B

  int lane = threadIdx.x & 63;
  int wib = threadIdx.x >> 6;
  int pairIdx = wib >> 1, khalf = wib & 1;
  int tile = blockIdx.x * 2 + pairIdx;   // 0..4799
  int n = tile >> 5;
  int ht = tile & 31;
  int mrow = lane & 15, quad = lane >> 4;
  int h = ht * 16 + mrow;
  uint32_t base = ((uint32_t)(n * 512 + h)) << 10;
  const float2* __restrict__ msrow = ms1 + (size_t)h * D_IN;

  f32x4 acc0 = {0.f, 0.f, 0.f, 0.f}, acc1 = {0.f, 0.f, 0.f, 0.f};

  int send = khalf * 16 + 16;
  for (int s = khalf * 16; s < send; ++s) {
    int kq = s * 32 + quad * 8;
    const f32x4* msq = (const f32x4*)(msrow + kq);
    f32x4 q0 = msq[0], q1 = msq[1], q2 = msq[2], q3 = msq[3];
    bf16x8 b0 = xf[(s * 2 + 0) * 64 + lane];
    bf16x8 b1 = xf[(s * 2 + 1) * 64 + lane];
    float eps[8];
    tf_normal8(k0, k1, k2, base + (uint32_t)kq, eps);
    float mu[8], sd[8];
    mu[0]=q0[0]; sd[0]=q0[1]; mu[1]=q0[2]; sd[1]=q0[3];
    mu[2]=q1[0]; sd[2]=q1[1]; mu[3]=q1[2]; sd[3]=q1[3];
    mu[4]=q2[0]; sd[4]=q2[1]; mu[5]=q2[2]; sd[5]=q2[3];
    mu[6]=q3[0]; sd[6]=q3[1]; mu[7]=q3[2]; sd[7]=q3[3];
    bf16x8 a;
#pragma unroll
    for (int j = 0; j < 8; ++j) a[j] = (__bf16)fmaf(eps[j], sd[j], mu[j]);
    acc0 = __builtin_amdgcn_mfma_f32_16x16x32_bf16(a, b0, acc0, 0, 0, 0);
    acc1 = __builtin_amdgcn_mfma_f32_16x16x32_bf16(a, b1, acc1, 0, 0, 0);
  }

  if (khalf) {
    lred[pairIdx][0][lane] = acc0;
    lred[pairIdx][1][lane] = acc1;
  }
  __syncthreads();
  if (!khalf) {
    f32x4 r0 = lred[pairIdx][0][lane], r1 = lred[pairIdx][1][lane];
    acc0 += r0; acc1 += r1;
    int hq = ht * 16 + quad * 4;
    float4 bias = *(const float4*)(b1s + n * 512 + hq);
    float bv[4] = {bias.x, bias.y, bias.z, bias.w};
    union { __bf16 v[4]; uint2 u; } p0, p1;
#pragma unroll
    for (int r = 0; r < 4; ++r) {
      p0.v[r] = (__bf16)fmaxf(acc0[r] + bv[r], 0.0f);
      p1.v[r] = (__bf16)fmaxf(acc1[r] + bv[r], 0.0f);
    }
    *(uint2*)(hB + ((size_t)(n * 32 + mrow) * 512 + hq)) = p0.u;
    *(uint2*)(hB + ((size_t)(n * 32 + 16 + mrow) * 512 + hq)) = p1.u;
  }
}

// ---------- layer 2: K-split 4, 9600 waves ----------
__global__ __launch_bounds__(256) void l2_kernel(
    const float* __restrict__ ws, float* __restrict__ y,
    uint32_t k0, uint32_t k1) {
  const float2* __restrict__ ms2 = (const float2*)(ws + OFF_MS2T);
  const bf16x8* __restrict__ hB8 = (const bf16x8*)(ws + OFF_HB);
  const float* __restrict__ b2s = ws + OFF_B2S;
  uint32_t k2 = k0 ^ k1 ^ 0x1BD11BDAu;

  __shared__ f32x4 lred[3][2][64];   // 6144 B

  int lane = threadIdx.x & 63;
  int wib = threadIdx.x >> 6;        // k-quarter 0..3
  int tile = blockIdx.x;             // 0..2399
  int n = tile >> 4;
  int ot = tile & 15;
  int mrow = lane & 15, quad = lane >> 4;
  int o = ot * 16 + mrow;
  uint32_t base = (uint32_t)(n * 256 + o) << 9;
  const float2* __restrict__ msrow = ms2 + (size_t)o * D_H;

  f32x4 acc0 = {0.f, 0.f, 0.f, 0.f}, acc1 = {0.f, 0.f, 0.f, 0.f};

  int send = wib * 4 + 4;
  for (int s = wib * 4; s < send; ++s) {
    int kq = s * 32 + quad * 8;
    const f32x4* msq = (const f32x4*)(msrow + kq);
    f32x4 q0 = msq[0], q1 = msq[1], q2 = msq[2], q3 = msq[3];
    bf16x8 b0 = hB8[(size_t)(n * 32 + mrow) * 64 + s * 4 + quad];
    bf16x8 b1 = hB8[(size_t)(n * 32 + 16 + mrow) * 64 + s * 4 + quad];
    float eps[8];
    tf_normal8(k0, k1, k2, base + (uint32_t)kq, eps);
    float mu[8], sd[8];
    mu[0]=q0[0]; sd[0]=q0[1]; mu[1]=q0[2]; sd[1]=q0[3];
    mu[2]=q1[0]; sd[2]=q1[1]; mu[3]=q1[2]; sd[3]=q1[3];
    mu[4]=q2[0]; sd[4]=q2[1]; mu[5]=q2[2]; sd[5]=q2[3];
    mu[6]=q3[0]; sd[6]=q3[1]; mu[7]=q3[2]; sd[7]=q3[3];
    bf16x8 a;
#pragma unroll
    for (int j = 0; j < 8; ++j) a[j] = (__bf16)fmaf(eps[j], sd[j], mu[j]);
    acc0 = __builtin_amdgcn_mfma_f32_16x16x32_bf16(a, b0, acc0, 0, 0, 0);
    acc1 = __builtin_amdgcn_mfma_f32_16x16x32_bf16(a, b1, acc1, 0, 0, 0);
  }

  if (wib) {
    lred[wib - 1][0][lane] = acc0;
    lred[wib - 1][1][lane] = acc1;
  }
  __syncthreads();
  if (!wib) {
#pragma unroll
    for (int c = 0; c < 3; ++c) {
      acc0 += lred[c][0][lane];
      acc1 += lred[c][1][lane];
    }
    int oq = ot * 16 + quad * 4;
    float4 bias = *(const float4*)(b2s + n * 256 + oq);
    float4 o0, o1;
    o0.x = acc0[0] + bias.x; o0.y = acc0[1] + bias.y;
    o0.z = acc0[2] + bias.z; o0.w = acc0[3] + bias.w;
    o1.x = acc1[0] + bias.x; o1.y = acc1[1] + bias.y;
    o1.z = acc1[2] + bias.z; o1.w = acc1[3] + bias.w;
    *(float4*)(y + (size_t)(n * 32 + mrow) * 256 + oq) = o0;
    *(float4*)(y + (size_t)(n * 32 + 16 + mrow) * 256 + oq) = o1;
  }
}

extern "C" void kernel_launch(void* const* d_in, const int* in_sizes, int n_in,
                              void* d_out, int out_size, void* d_ws, size_t ws_size,
                              hipStream_t stream) {
  const float* x = (const float*)d_in[0];
  const float* muW1 = (const float*)d_in[1];
  const float* mub1 = (const float*)d_in[2];
  const float* muW2 = (const float*)d_in[3];
  const float* mub2 = (const float*)d_in[4];
  const float* vW1 = (const float*)d_in[5];
  const float* vb1 = (const float*)d_in[6];
  const float* vW2 = (const float*)d_in[7];
  const float* vb2 = (const float*)d_in[8];
  float* y = (float*)d_out;
  float* ws = (float*)d_ws;

  uint32_t nk[4][2];
  for (uint32_t j = 0; j < 4; ++j) {
    threefry2x32(0u, 42u, 0u, j, nk[j][0], nk[j][1]);
  }
  // eW1=nk[0], eb1=nk[1], eW2=nk[2], eb2=nk[3]

  prep_kernel<<<3138, 256, 0, stream>>>(
      x, muW1, vW1, muW2, vW2, mub1, vb1, mub2, vb2, ws,
      nk[1][0], nk[1][1], nk[3][0], nk[3][1]);

  // l1: 4800 tiles x 2 k-halves = 9600 waves -> 2400 blocks x 256
  l1_kernel<<<2400, 256, 0, stream>>>(ws, nk[0][0], nk[0][1]);

  // l2: 2400 tiles x 4 k-quarters = 9600 waves -> 2400 blocks x 256
  l2_kernel<<<2400, 256, 0, stream>>>(ws, y, nk[2][0], nk[2][1]);
}

// Round 12
// 301.376 us; speedup vs baseline: 11.7328x; 1.1539x over previous
//
#include <hip/hip_runtime.h>
#include <stdint.h>

#define NS 150
#define D_IN 1024
#define D_H 512
#define D_OUT 256

typedef __bf16 bf16x8 __attribute__((ext_vector_type(8)));
typedef float f32x4 __attribute__((ext_vector_type(4)));

// ---- workspace layout (float offsets) ----
#define OFF_XF    0u          // x fragments, 32768 bf16 (MFMA B-operand order)
#define OFF_MS1T  16384u      // float2[512*1024] (mu,std) at [h][i]
#define OFF_MS2T  1064960u    // float2[256*512]  (mu,std) at [o][h]
#define OFF_B1S   1327104u    // 150*512 = 76800
#define OFF_B2S   1403904u    // 150*256 = 38400
#define OFF_HB    1442304u    // h bf16 [n][b][h]: 150*32*512 bf16

// ---------- threefry-2x32 (JAX-exact, 20 rounds) ----------
#define ROTL32(x, r) __builtin_rotateleft32((x), (r))

__host__ __device__ __forceinline__ void threefry2x32(uint32_t k0, uint32_t k1,
                                                      uint32_t x0, uint32_t x1,
                                                      uint32_t& o0, uint32_t& o1) {
  uint32_t k2 = k0 ^ k1 ^ 0x1BD11BDAu;
  x0 += k0; x1 += k1;
#define TFR(r) { x0 += x1; x1 = ROTL32(x1, r); x1 ^= x0; }
  TFR(13) TFR(15) TFR(26) TFR(6)
  x0 += k1; x1 += k2 + 1u;
  TFR(17) TFR(29) TFR(16) TFR(24)
  x0 += k2; x1 += k0 + 2u;
  TFR(13) TFR(15) TFR(26) TFR(6)
  x0 += k0; x1 += k1 + 3u;
  TFR(17) TFR(29) TFR(16) TFR(24)
  x0 += k1; x1 += k2 + 4u;
  TFR(13) TFR(15) TFR(26) TFR(6)
  x0 += k2; x1 += k0 + 5u;
#undef TFR
  o0 = x0; o1 = x1;
}

// scalar path (prep biases)
__device__ __forceinline__ float tf_normal(uint32_t k0, uint32_t k1, uint32_t idx) {
  uint32_t o0, o1;
  threefry2x32(k0, k1, 0u, idx, o0, o1);
  uint32_t bits = o0 ^ o1;
  uint32_t fb = (bits >> 9) | 0x3F800000u;
  float m = __uint_as_float(fb);
  const float lo = -0.99999994f;
  float u = fmaxf(fmaf(m, 2.0f, -3.0f), lo);
  float t = fmaf(u, -u, 1.0f);
  float w = -0.69314718056f * __builtin_amdgcn_logf(t);
  const float S = 1.41421354f;
  float p;
  if (w < 5.0f) {
    float ww = w - 2.5f;
    p = S * 2.81022636e-08f;
    p = fmaf(p, ww, S * 3.43273939e-07f);
    p = fmaf(p, ww, S * -3.5233877e-06f);
    p = fmaf(p, ww, S * -4.39150654e-06f);
    p = fmaf(p, ww, S * 0.00021858087f);
    p = fmaf(p, ww, S * -0.00125372503f);
    p = fmaf(p, ww, S * -0.00417768164f);
    p = fmaf(p, ww, S * 0.246640727f);
    p = fmaf(p, ww, S * 1.50140941f);
  } else {
    float ww = __builtin_amdgcn_sqrtf(w) - 3.0f;
    p = S * -0.000200214257f;
    p = fmaf(p, ww, S * 0.000100950558f);
    p = fmaf(p, ww, S * 0.00134934322f);
    p = fmaf(p, ww, S * -0.00367342844f);
    p = fmaf(p, ww, S * 0.00573950773f);
    p = fmaf(p, ww, S * -0.0076224613f);
    p = fmaf(p, ww, S * 0.00943887047f);
    p = fmaf(p, ww, S * 1.00167406f);
    p = fmaf(p, ww, S * 2.83297682f);
  }
  return p * u;
}

// ---------- 8-chain threefry: INLINE ASM, hand-scheduled ----------
// 20 rounds x (8 add + 8 alignbit + 8 xor) + 5 injections x 16 adds = 560
// instrs, op-grouped across the 8 independent chains (explicit ILP=8).
// rotl(x,r) = v_alignbit_b32(x, x, 32-r). Key consts in SGPRs. 16 "+v"
// operands force the allocator to keep all chain state simultaneously live
// (C-level unrolls kept getting re-serialized: R9-R11 all 40 VGPR / 248us).
#define TF_ADD8 \
  "v_add_u32 %[a0], %[a0], %[b0]\n\t" "v_add_u32 %[a1], %[a1], %[b1]\n\t" \
  "v_add_u32 %[a2], %[a2], %[b2]\n\t" "v_add_u32 %[a3], %[a3], %[b3]\n\t" \
  "v_add_u32 %[a4], %[a4], %[b4]\n\t" "v_add_u32 %[a5], %[a5], %[b5]\n\t" \
  "v_add_u32 %[a6], %[a6], %[b6]\n\t" "v_add_u32 %[a7], %[a7], %[b7]\n\t"
#define TF_ROT8(sh) \
  "v_alignbit_b32 %[b0], %[b0], %[b0], " sh "\n\t" \
  "v_alignbit_b32 %[b1], %[b1], %[b1], " sh "\n\t" \
  "v_alignbit_b32 %[b2], %[b2], %[b2], " sh "\n\t" \
  "v_alignbit_b32 %[b3], %[b3], %[b3], " sh "\n\t" \
  "v_alignbit_b32 %[b4], %[b4], %[b4], " sh "\n\t" \
  "v_alignbit_b32 %[b5], %[b5], %[b5], " sh "\n\t" \
  "v_alignbit_b32 %[b6], %[b6], %[b6], " sh "\n\t" \
  "v_alignbit_b32 %[b7], %[b7], %[b7], " sh "\n\t"
#define TF_XOR8 \
  "v_xor_b32 %[b0], %[b0], %[a0]\n\t" "v_xor_b32 %[b1], %[b1], %[a1]\n\t" \
  "v_xor_b32 %[b2], %[b2], %[a2]\n\t" "v_xor_b32 %[b3], %[b3], %[a3]\n\t" \
  "v_xor_b32 %[b4], %[b4], %[a4]\n\t" "v_xor_b32 %[b5], %[b5], %[a5]\n\t" \
  "v_xor_b32 %[b6], %[b6], %[a6]\n\t" "v_xor_b32 %[b7], %[b7], %[a7]\n\t"
#define TF_ROUND(sh) TF_ADD8 TF_ROT8(sh) TF_XOR8
#define TF_INJ(KA, KB) \
  "v_add_u32 %[a0], " KA ", %[a0]\n\t" "v_add_u32 %[a1], " KA ", %[a1]\n\t" \
  "v_add_u32 %[a2], " KA ", %[a2]\n\t" "v_add_u32 %[a3], " KA ", %[a3]\n\t" \
  "v_add_u32 %[a4], " KA ", %[a4]\n\t" "v_add_u32 %[a5], " KA ", %[a5]\n\t" \
  "v_add_u32 %[a6], " KA ", %[a6]\n\t" "v_add_u32 %[a7], " KA ", %[a7]\n\t" \
  "v_add_u32 %[b0], " KB ", %[b0]\n\t" "v_add_u32 %[b1], " KB ", %[b1]\n\t" \
  "v_add_u32 %[b2], " KB ", %[b2]\n\t" "v_add_u32 %[b3], " KB ", %[b3]\n\t" \
  "v_add_u32 %[b4], " KB ", %[b4]\n\t" "v_add_u32 %[b5], " KB ", %[b5]\n\t" \
  "v_add_u32 %[b6], " KB ", %[b6]\n\t" "v_add_u32 %[b7], " KB ", %[b7]\n\t"

// rotl 13,15,26,6 -> shifts 19,17,6,26 ; rotl 17,29,16,24 -> 15,3,16,8
__device__ __forceinline__ void tf8_bits(uint32_t k0, uint32_t k1, uint32_t k2,
                                         uint32_t idx0, uint32_t* bits) {
  uint32_t k2p1 = k2 + 1u, k0p2 = k0 + 2u, k1p3 = k1 + 3u;
  uint32_t k2p4 = k2 + 4u, k0p5 = k0 + 5u;
  uint32_t t0 = idx0 + k1;
  uint32_t a0 = k0, a1 = k0, a2 = k0, a3 = k0, a4 = k0, a5 = k0, a6 = k0, a7 = k0;
  uint32_t b0 = t0, b1 = t0 + 1u, b2 = t0 + 2u, b3 = t0 + 3u;
  uint32_t b4 = t0 + 4u, b5 = t0 + 5u, b6 = t0 + 6u, b7 = t0 + 7u;
  asm(TF_ROUND("19") TF_ROUND("17") TF_ROUND("6") TF_ROUND("26")
      TF_INJ("%[k1]", "%[k2p1]")
      TF_ROUND("15") TF_ROUND("3") TF_ROUND("16") TF_ROUND("8")
      TF_INJ("%[k2]", "%[k0p2]")
      TF_ROUND("19") TF_ROUND("17") TF_ROUND("6") TF_ROUND("26")
      TF_INJ("%[k0]", "%[k1p3]")
      TF_ROUND("15") TF_ROUND("3") TF_ROUND("16") TF_ROUND("8")
      TF_INJ("%[k1]", "%[k2p4]")
      TF_ROUND("19") TF_ROUND("17") TF_ROUND("6") TF_ROUND("26")
      TF_INJ("%[k2]", "%[k0p5]")
      : [a0]"+v"(a0), [a1]"+v"(a1), [a2]"+v"(a2), [a3]"+v"(a3),
        [a4]"+v"(a4), [a5]"+v"(a5), [a6]"+v"(a6), [a7]"+v"(a7),
        [b0]"+v"(b0), [b1]"+v"(b1), [b2]"+v"(b2), [b3]"+v"(b3),
        [b4]"+v"(b4), [b5]"+v"(b5), [b6]"+v"(b6), [b7]"+v"(b7)
      : [k0]"s"(k0), [k1]"s"(k1), [k2]"s"(k2), [k2p1]"s"(k2p1),
        [k0p2]"s"(k0p2), [k1p3]"s"(k1p3), [k2p4]"s"(k2p4), [k0p5]"s"(k0p5));
  bits[0] = a0 ^ b0; bits[1] = a1 ^ b1; bits[2] = a2 ^ b2; bits[3] = a3 ^ b3;
  bits[4] = a4 ^ b4; bits[5] = a5 ^ b5; bits[6] = a6 ^ b6; bits[7] = a7 ^ b7;
}

__device__ __forceinline__ float bits_normal(uint32_t bits) {
  uint32_t fb = (bits >> 9) | 0x3F800000u;
  float m = __uint_as_float(fb);
  const float lo = -0.99999994f;
  float u = fmaxf(fmaf(m, 2.0f, -3.0f), lo);
  float t = fmaf(u, -u, 1.0f);
  float w = -0.69314718056f * __builtin_amdgcn_logf(t);
  const float S = 1.41421354f;
  float p;
  if (w < 5.0f) {
    float ww = w - 2.5f;
    p = S * 2.81022636e-08f;
    p = fmaf(p, ww, S * 3.43273939e-07f);
    p = fmaf(p, ww, S * -3.5233877e-06f);
    p = fmaf(p, ww, S * -4.39150654e-06f);
    p = fmaf(p, ww, S * 0.00021858087f);
    p = fmaf(p, ww, S * -0.00125372503f);
    p = fmaf(p, ww, S * -0.00417768164f);
    p = fmaf(p, ww, S * 0.246640727f);
    p = fmaf(p, ww, S * 1.50140941f);
  } else {
    float ww = __builtin_amdgcn_sqrtf(w) - 3.0f;
    p = S * -0.000200214257f;
    p = fmaf(p, ww, S * 0.000100950558f);
    p = fmaf(p, ww, S * 0.00134934322f);
    p = fmaf(p, ww, S * -0.00367342844f);
    p = fmaf(p, ww, S * 0.00573950773f);
    p = fmaf(p, ww, S * -0.0076224613f);
    p = fmaf(p, ww, S * 0.00943887047f);
    p = fmaf(p, ww, S * 1.00167406f);
    p = fmaf(p, ww, S * 2.83297682f);
  }
  return p * u;
}

// ---------- prep ----------
__global__ __launch_bounds__(256) void prep_kernel(
    const float* __restrict__ x,
    const float* __restrict__ muW1, const float* __restrict__ vW1,
    const float* __restrict__ muW2, const float* __restrict__ vW2,
    const float* __restrict__ mub1, const float* __restrict__ vb1,
    const float* __restrict__ mub2, const float* __restrict__ vb2,
    float* __restrict__ ws,
    uint32_t kb1_0, uint32_t kb1_1, uint32_t kb2_0, uint32_t kb2_1) {
  int bb = blockIdx.x;
  int tid = threadIdx.x;
  if (bb < 2048) {
    int t = bb * 256 + tid;                       // [h][i] flat
    ((float2*)(ws + OFF_MS1T))[t] = make_float2(muW1[t], expf(vW1[t]));
  } else if (bb < 2560) {
    int t = (bb - 2048) * 256 + tid;              // [o][h] flat
    ((float2*)(ws + OFF_MS2T))[t] = make_float2(muW2[t], expf(vW2[t]));
  } else if (bb < 2688) {
    int t = (bb - 2560) * 256 + tid;              // x fragments, B-operand order
    int j = t & 7, lane = (t >> 3) & 63, fidx = t >> 9;
    int s = fidx >> 1, f = fidx & 1;
    int b = f * 16 + (lane & 15);
    int k = s * 32 + ((lane >> 4) << 3) + j;
    ((__bf16*)(ws + OFF_XF))[t] = (__bf16)x[b * D_IN + k];
  } else if (bb < 2988) {
    int t = (bb - 2688) * 256 + tid;              // b1s
    int h = t & 511;
    float eps = tf_normal(kb1_0, kb1_1, (uint32_t)t);
    ws[OFF_B1S + t] = fmaf(eps, expf(vb1[h]), mub1[h]);
  } else {
    int t = (bb - 2988) * 256 + tid;              // b2s
    int o = t & 255;
    float eps = tf_normal(kb2_0, kb2_1, (uint32_t)t);
    ws[OFF_B2S + t] = fmaf(eps, expf(vb2[o]), mub2[o]);
  }
}

// ---------- layer 1: K-split 2, 9600 waves; A-frags via asm threefry ----------
__global__ __launch_bounds__(256) void l1_kernel(
    const float* __restrict__ ws, uint32_t k0, uint32_t k1) {
  const float2* __restrict__ ms1 = (const float2*)(ws + OFF_MS1T);
  const bf16x8* __restrict__ xf = (const bf16x8*)(ws + OFF_XF);
  const float* __restrict__ b1s = ws + OFF_B1S;
  __bf16* __restrict__ hB = (__bf16*)(ws + OFF_HB);
  uint32_t k2 = k0 ^ k1 ^ 0x1BD11BDAu;

  __shared__ f32x4 lred[2][2][64];   // 4096 B

  int lane = threadIdx.x & 63;
  int wib = threadIdx.x >> 6;
  int pairIdx = wib >> 1, khalf = wib & 1;
  int tile = blockIdx.x * 2 + pairIdx;   // 0..4799
  int n = tile >> 5;
  int ht = tile & 31;
  int mrow = lane & 15, quad = lane >> 4;
  int h = ht * 16 + mrow;
  uint32_t base = ((uint32_t)(n * 512 + h)) << 10;
  const float2* __restrict__ msrow = ms1 + (size_t)h * D_IN;

  f32x4 acc0 = {0.f, 0.f, 0.f, 0.f}, acc1 = {0.f, 0.f, 0.f, 0.f};

  int send = khalf * 16 + 16;
  for (int s = khalf * 16; s < send; ++s) {
    int kq = s * 32 + quad * 8;
    const f32x4* msq = (const f32x4*)(msrow + kq);
    f32x4 q0 = msq[0], q1 = msq[1], q2 = msq[2], q3 = msq[3];
    bf16x8 b0 = xf[(s * 2 + 0) * 64 + lane];
    bf16x8 b1 = xf[(s * 2 + 1) * 64 + lane];
    uint32_t bits[8];
    tf8_bits(k0, k1, k2, base + (uint32_t)kq, bits);
    float mu[8], sd[8];
    mu[0]=q0[0]; sd[0]=q0[1]; mu[1]=q0[2]; sd[1]=q0[3];
    mu[2]=q1[0]; sd[2]=q1[1]; mu[3]=q1[2]; sd[3]=q1[3];
    mu[4]=q2[0]; sd[4]=q2[1]; mu[5]=q2[2]; sd[5]=q2[3];
    mu[6]=q3[0]; sd[6]=q3[1]; mu[7]=q3[2]; sd[7]=q3[3];
    bf16x8 a;
#pragma unroll
    for (int j = 0; j < 8; ++j) {
      float eps = bits_normal(bits[j]);
      a[j] = (__bf16)fmaf(eps, sd[j], mu[j]);
    }
    acc0 = __builtin_amdgcn_mfma_f32_16x16x32_bf16(a, b0, acc0, 0, 0, 0);
    acc1 = __builtin_amdgcn_mfma_f32_16x16x32_bf16(a, b1, acc1, 0, 0, 0);
  }

  if (khalf) {
    lred[pairIdx][0][lane] = acc0;
    lred[pairIdx][1][lane] = acc1;
  }
  __syncthreads();
  if (!khalf) {
    f32x4 r0 = lred[pairIdx][0][lane], r1 = lred[pairIdx][1][lane];
    acc0 += r0; acc1 += r1;
    int hq = ht * 16 + quad * 4;
    float4 bias = *(const float4*)(b1s + n * 512 + hq);
    float bv[4] = {bias.x, bias.y, bias.z, bias.w};
    union { __bf16 v[4]; uint2 u; } p0, p1;
#pragma unroll
    for (int r = 0; r < 4; ++r) {
      p0.v[r] = (__bf16)fmaxf(acc0[r] + bv[r], 0.0f);
      p1.v[r] = (__bf16)fmaxf(acc1[r] + bv[r], 0.0f);
    }
    *(uint2*)(hB + ((size_t)(n * 32 + mrow) * 512 + hq)) = p0.u;
    *(uint2*)(hB + ((size_t)(n * 32 + 16 + mrow) * 512 + hq)) = p1.u;
  }
}

// ---------- layer 2: K-split 4, 9600 waves ----------
__global__ __launch_bounds__(256) void l2_kernel(
    const float* __restrict__ ws, float* __restrict__ y,
    uint32_t k0, uint32_t k1) {
  const float2* __restrict__ ms2 = (const float2*)(ws + OFF_MS2T);
  const bf16x8* __restrict__ hB8 = (const bf16x8*)(ws + OFF_HB);
  const float* __restrict__ b2s = ws + OFF_B2S;
  uint32_t k2 = k0 ^ k1 ^ 0x1BD11BDAu;

  __shared__ f32x4 lred[3][2][64];   // 6144 B

  int lane = threadIdx.x & 63;
  int wib = threadIdx.x >> 6;        // k-quarter 0..3
  int tile = blockIdx.x;             // 0..2399
  int n = tile >> 4;
  int ot = tile & 15;
  int mrow = lane & 15, quad = lane >> 4;
  int o = ot * 16 + mrow;
  uint32_t base = (uint32_t)(n * 256 + o) << 9;
  const float2* __restrict__ msrow = ms2 + (size_t)o * D_H;

  f32x4 acc0 = {0.f, 0.f, 0.f, 0.f}, acc1 = {0.f, 0.f, 0.f, 0.f};

  int send = wib * 4 + 4;
  for (int s = wib * 4; s < send; ++s) {
    int kq = s * 32 + quad * 8;
    const f32x4* msq = (const f32x4*)(msrow + kq);
    f32x4 q0 = msq[0], q1 = msq[1], q2 = msq[2], q3 = msq[3];
    bf16x8 b0 = hB8[(size_t)(n * 32 + mrow) * 64 + s * 4 + quad];
    bf16x8 b1 = hB8[(size_t)(n * 32 + 16 + mrow) * 64 + s * 4 + quad];
    uint32_t bits[8];
    tf8_bits(k0, k1, k2, base + (uint32_t)kq, bits);
    float mu[8], sd[8];
    mu[0]=q0[0]; sd[0]=q0[1]; mu[1]=q0[2]; sd[1]=q0[3];
    mu[2]=q1[0]; sd[2]=q1[1]; mu[3]=q1[2]; sd[3]=q1[3];
    mu[4]=q2[0]; sd[4]=q2[1]; mu[5]=q2[2]; sd[5]=q2[3];
    mu[6]=q3[0]; sd[6]=q3[1]; mu[7]=q3[2]; sd[7]=q3[3];
    bf16x8 a;
#pragma unroll
    for (int j = 0; j < 8; ++j) {
      float eps = bits_normal(bits[j]);
      a[j] = (__bf16)fmaf(eps, sd[j], mu[j]);
    }
    acc0 = __builtin_amdgcn_mfma_f32_16x16x32_bf16(a, b0, acc0, 0, 0, 0);
    acc1 = __builtin_amdgcn_mfma_f32_16x16x32_bf16(a, b1, acc1, 0, 0, 0);
  }

  if (wib) {
    lred[wib - 1][0][lane] = acc0;
    lred[wib - 1][1][lane] = acc1;
  }
  __syncthreads();
  if (!wib) {
#pragma unroll
    for (int c = 0; c < 3; ++c) {
      acc0 += lred[c][0][lane];
      acc1 += lred[c][1][lane];
    }
    int oq = ot * 16 + quad * 4;
    float4 bias = *(const float4*)(b2s + n * 256 + oq);
    float4 o0, o1;
    o0.x = acc0[0] + bias.x; o0.y = acc0[1] + bias.y;
    o0.z = acc0[2] + bias.z; o0.w = acc0[3] + bias.w;
    o1.x = acc1[0] + bias.x; o1.y = acc1[1] + bias.y;
    o1.z = acc1[2] + bias.z; o1.w = acc1[3] + bias.w;
    *(float4*)(y + (size_t)(n * 32 + mrow) * 256 + oq) = o0;
    *(float4*)(y + (size_t)(n * 32 + 16 + mrow) * 256 + oq) = o1;
  }
}

extern "C" void kernel_launch(void* const* d_in, const int* in_sizes, int n_in,
                              void* d_out, int out_size, void* d_ws, size_t ws_size,
                              hipStream_t stream) {
  const float* x = (const float*)d_in[0];
  const float* muW1 = (const float*)d_in[1];
  const float* mub1 = (const float*)d_in[2];
  const float* muW2 = (const float*)d_in[3];
  const float* mub2 = (const float*)d_in[4];
  const float* vW1 = (const float*)d_in[5];
  const float* vb1 = (const float*)d_in[6];
  const float* vW2 = (const float*)d_in[7];
  const float* vb2 = (const float*)d_in[8];
  float* y = (float*)d_out;
  float* ws = (float*)d_ws;

  uint32_t nk[4][2];
  for (uint32_t j = 0; j < 4; ++j) {
    threefry2x32(0u, 42u, 0u, j, nk[j][0], nk[j][1]);
  }
  // eW1=nk[0], eb1=nk[1], eW2=nk[2], eb2=nk[3]

  prep_kernel<<<3138, 256, 0, stream>>>(
      x, muW1, vW1, muW2, vW2, mub1, vb1, mub2, vb2, ws,
      nk[1][0], nk[1][1], nk[3][0], nk[3][1]);

  // l1: 4800 tiles x 2 k-halves = 9600 waves -> 2400 blocks x 256
  l1_kernel<<<2400, 256, 0, stream>>>(ws, nk[0][0], nk[0][1]);

  // l2: 2400 tiles x 4 k-quarters = 9600 waves -> 2400 blocks x 256
  l2_kernel<<<2400, 256, 0, stream>>>(ws, y, nk[2][0], nk[2][1]);
}